// Round 11
// baseline (1016.732 us; speedup 1.0000x reference)
//
#include <hip/hip_runtime.h>
#include <math.h>

#define NN 100000
#define NE 1600000
#define HID 128
#define INCH 256
#define OUTC 40
#define NLAYERS 8
#define NBUCK 391   // ceil(NN/256)
#define EPB 4096
#define CAP 6144
#define LW 136      // LDS row stride in ushorts (272 B)

typedef __attribute__((ext_vector_type(8))) short bf16x8;
typedef __attribute__((ext_vector_type(4))) float f32x4;

static __device__ inline unsigned short f2bf(float f) {
  unsigned u = __float_as_uint(f);
  unsigned r = (u + 0x7fff + ((u >> 16) & 1)) >> 16;
  return (unsigned short)r;
}
static __device__ inline float bflo(unsigned u) { return __uint_as_float(u << 16); }
static __device__ inline float bfhi(unsigned u) { return __uint_as_float(u & 0xffff0000u); }

// acc += a.lo*b.lo + a.hi*b.hi (bf16 pairs, f32 accum)
static __device__ inline float dot2bf(float c, unsigned a, unsigned b) {
  asm("v_dot2_f32_bf16 %0, %1, %2, %0" : "+v"(c) : "v"(a), "v"(b));
  return c;
}
// pack (bf16(lo), bf16(hi)) into one dword
static __device__ inline unsigned cvtpk(float lo, float hi) {
  unsigned r;
  asm("v_cvt_pk_bf16_f32 %0, %1, %2" : "=v"(r) : "v"(lo), "v"(hi));
  return r;
}

// ---------------- preprocessing (atomic-light counting sort) ----------------

static __global__ void k_zerob(int* __restrict__ bcnt) {
  int i = blockIdx.x * 256 + threadIdx.x;
  if (i < NBUCK) bcnt[i] = 0;
}

static __global__ __launch_bounds__(256) void k_bhist(const int* __restrict__ ei,
                                                      int* __restrict__ bcnt) {
  __shared__ int lh[NBUCK + 1];
  int t = threadIdx.x;
  for (int i = t; i <= NBUCK; i += 256) lh[i] = 0;
  __syncthreads();
  int e0 = blockIdx.x * EPB;
  for (int k = t; k < EPB; k += 256) {
    int e = e0 + k;
    if (e < NE) atomicAdd(&lh[ei[NE + e] >> 8], 1);
  }
  __syncthreads();
  for (int i = t; i < NBUCK; i += 256)
    if (lh[i]) atomicAdd(&bcnt[i], lh[i]);
}

static __global__ void k_bscan(const int* __restrict__ bcnt, int* __restrict__ boffs,
                               int* __restrict__ bcur, int* __restrict__ offs) {
  __shared__ int sd[512];
  int t = threadIdx.x;
  sd[t] = (t < NBUCK) ? bcnt[t] : 0;
  __syncthreads();
  for (int d = 1; d < 512; d <<= 1) {
    int v = (t >= d) ? sd[t - d] : 0;
    __syncthreads();
    sd[t] += v;
    __syncthreads();
  }
  if (t < NBUCK) {
    boffs[t + 1] = sd[t];
    bcur[t] = sd[t] - bcnt[t];
  }
  if (t == 0) { boffs[0] = 0; offs[NN] = NE; }
}

static __global__ __launch_bounds__(256) void k_sortA(const int* __restrict__ ei,
                                                      int* __restrict__ bcur,
                                                      int2* __restrict__ stage) {
  __shared__ int lsrc[EPB], ldst[EPB];
  __shared__ int lh[NBUCK + 1], lbase[NBUCK + 1], lcur[NBUCK + 1];
  int t = threadIdx.x;
  int e0 = blockIdx.x * EPB;
  for (int k = t; k < EPB; k += 256) {
    int e = e0 + k;
    lsrc[k] = (e < NE) ? ei[e] : -1;
    ldst[k] = (e < NE) ? ei[NE + e] : -1;
  }
  for (int i = t; i <= NBUCK; i += 256) lh[i] = 0;
  __syncthreads();
  for (int k = t; k < EPB; k += 256)
    if (ldst[k] >= 0) atomicAdd(&lh[ldst[k] >> 8], 1);
  __syncthreads();
  for (int i = t; i < NBUCK; i += 256) {
    int c = lh[i];
    lbase[i] = c ? atomicAdd(&bcur[i], c) : 0;
    lcur[i] = 0;
  }
  __syncthreads();
  for (int k = t; k < EPB; k += 256) {
    int d = ldst[k];
    if (d >= 0) {
      int bu = d >> 8;
      int r = atomicAdd(&lcur[bu], 1);
      stage[lbase[bu] + r] = make_int2(lsrc[k], d);
    }
  }
}

static __global__ __launch_bounds__(256) void k_degs(
    const int2* __restrict__ stage, const int* __restrict__ boffs,
    int* __restrict__ offs, float* __restrict__ dinv, int* __restrict__ cursor) {
  __shared__ int lcnt[256];
  __shared__ int sd[256];
  int b = blockIdx.x, t = threadIdx.x;
  int sb = boffs[b], se = boffs[b + 1];
  int cntb = se - sb;
  int nb0 = b << 8;
  lcnt[t] = 0;
  __syncthreads();
  for (int k = t; k < cntb; k += 256) atomicAdd(&lcnt[stage[sb + k].y - nb0], 1);
  __syncthreads();
  int v = lcnt[t];
  sd[t] = v;
  __syncthreads();
  for (int d = 1; d < 256; d <<= 1) {
    int u = (t >= d) ? sd[t - d] : 0;
    __syncthreads();
    sd[t] += u;
    __syncthreads();
  }
  int n = nb0 + t;
  if (n < NN) {
    int o = sb + sd[t] - v;
    offs[n] = o;
    cursor[n] = o;
    dinv[n] = rsqrtf((float)(v + 1));
  }
}

// weight: 0.5*dinv*dinv as duplicated bf16 pair (for dot2 masks)
static __global__ __launch_bounds__(256) void k_passB2(
    const int2* __restrict__ stage, const int* __restrict__ boffs,
    const int* __restrict__ offs, const float* __restrict__ dinv,
    int* __restrict__ cursor, int2* __restrict__ edata) {
  __shared__ int2 lbuf[CAP];
  __shared__ int lcur[256];
  int b = blockIdx.x, t = threadIdx.x;
  int sb = boffs[b], se = boffs[b + 1];
  int cntb = se - sb;
  int nb0 = b << 8;
  if (cntb <= CAP) {
    if (nb0 + t < NN) lcur[t] = offs[nb0 + t] - sb;
    __syncthreads();
    for (int k = t; k < cntb; k += 256) {
      int2 sd_ = stage[sb + k];
      unsigned wb = f2bf(0.5f * dinv[sd_.x] * dinv[sd_.y]);
      int p = atomicAdd(&lcur[sd_.y - nb0], 1);
      lbuf[p] = make_int2(sd_.x, (int)((wb << 16) | wb));
    }
    __syncthreads();
    for (int k = t; k < cntb; k += 256) edata[sb + k] = lbuf[k];
  } else {
    for (int k = t; k < cntb; k += 256) {
      int2 sd_ = stage[sb + k];
      unsigned wb = f2bf(0.5f * dinv[sd_.x] * dinv[sd_.y]);
      int p = atomicAdd(&cursor[sd_.y], 1);
      edata[p] = make_int2(sd_.x, (int)((wb << 16) | wb));
    }
  }
}

// ---------------- weight conversion ----------------
static __global__ void k_cvtw(const float* __restrict__ W, unsigned short* __restrict__ Wt,
                              int K) {
  int idx = blockIdx.x * 256 + threadIdx.x;
  if (idx < K * HID) {
    int k = idx >> 7, n = idx & 127;
    Wt[(size_t)n * K + k] = f2bf(W[idx]);
  }
}

// Folded layer weights: W'_l = beta_l * W_l + (1-beta_l) * I, transposed [n][k]
static __global__ void k_cvtw8(const float* __restrict__ W, unsigned short* __restrict__ Wt) {
  int idx = blockIdx.x * 256 + threadIdx.x;
  if (idx < NLAYERS * HID * HID) {
    int l = idx >> 14, rem = idx & 16383;
    int k = rem >> 7, n = rem & 127;
    float beta = logf(1.0f / (float)(l + 1) + 1.0f);
    float v = beta * W[idx];
    if (k == n) v += 1.0f - beta;
    Wt[(size_t)l * HID * HID + n * HID + k] = f2bf(v);
  }
}

static __global__ void k_cvtw2(const float* __restrict__ W2, unsigned short* __restrict__ Wt2) {
  int idx = blockIdx.x * 256 + threadIdx.x;
  if (idx < 48 * HID) {
    int n = idx >> 7, k = idx & 127;
    Wt2[idx] = (n < OUTC) ? f2bf(W2[(size_t)k * OUTC + n]) : 0;
  }
}

// ---------------- lin1: C16[M x 128] = bf16(relu(A32[M x 256] @ W + bias)) ----------------
__global__ __launch_bounds__(256, 3) void k_lin1(
    const float* __restrict__ A32, const unsigned short* __restrict__ Wt16,
    const float* __restrict__ bias, unsigned short* __restrict__ C16, int M) {
  __shared__ unsigned short lds[128 * LW];
  const int tid = threadIdx.x;
  const int lane = tid & 63;
  const int wid = tid >> 6;
  const int j = lane & 15, g = lane >> 4;
  const int rowhalf = (wid >> 1) * 64;
  const int colbase = (wid & 1) * 64;
  const int m0 = blockIdx.x * 128;

  f32x4 acc[4][4];
  const f32x4 zero = {0.f, 0.f, 0.f, 0.f};
#pragma unroll
  for (int rt = 0; rt < 4; ++rt)
#pragma unroll
    for (int c = 0; c < 4; ++c) acc[rt][c] = zero;

#pragma unroll 1
  for (int kc = 0; kc < 2; ++kc) {
    bf16x8 bfrag[4][4];
#pragma unroll
    for (int c = 0; c < 4; ++c)
#pragma unroll
      for (int s = 0; s < 4; ++s)
        bfrag[c][s] = *(const bf16x8*)(Wt16 + (size_t)(colbase + 16 * c + j) * INCH +
                                       kc * 128 + 32 * s + 8 * g);
    __syncthreads();
#pragma unroll 2
    for (int i = 0; i < 8; ++i) {
      int idx = i * 256 + tid;
      int row = idx >> 4, ch = idx & 15;
      int grow = m0 + row;
      if (grow >= M) grow = M - 1;
      const float* p = A32 + (size_t)grow * INCH + kc * 128 + ch * 8;
      float4 u0 = *(const float4*)p;
      float4 u1 = *(const float4*)(p + 4);
      bf16x8 v;
      v[0] = (short)f2bf(u0.x); v[1] = (short)f2bf(u0.y);
      v[2] = (short)f2bf(u0.z); v[3] = (short)f2bf(u0.w);
      v[4] = (short)f2bf(u1.x); v[5] = (short)f2bf(u1.y);
      v[6] = (short)f2bf(u1.z); v[7] = (short)f2bf(u1.w);
      *(bf16x8*)&lds[row * LW + ch * 8] = v;
    }
    __syncthreads();
#pragma unroll
    for (int rt = 0; rt < 4; ++rt) {
      bf16x8 af[4];
#pragma unroll
      for (int s = 0; s < 4; ++s)
        af[s] = *(const bf16x8*)&lds[(rowhalf + rt * 16 + j) * LW + 32 * s + 8 * g];
#pragma unroll
      for (int s = 0; s < 4; ++s)
#pragma unroll
        for (int c = 0; c < 4; ++c)
          acc[rt][c] =
              __builtin_amdgcn_mfma_f32_16x16x32_bf16(af[s], bfrag[c][s], acc[rt][c], 0, 0, 0);
    }
  }

#pragma unroll
  for (int rt = 0; rt < 4; ++rt)
#pragma unroll
    for (int i = 0; i < 4; ++i) {
      const int rr = m0 + rowhalf + rt * 16 + 4 * g + i;
      if (rr >= M) continue;
#pragma unroll
      for (int c = 0; c < 4; ++c) {
        const int col = colbase + 16 * c + j;
        float z = fmaxf(acc[rt][c][i] + bias[col], 0.f);
        C16[(size_t)rr * HID + col] = f2bf(z);
      }
    }
}

// ---------------- fused layer: agg (wave-uniform gather, dot2) + GEMM ----------------
// Block = 64 nodes = 4 waves. Phase 1: wave w handles nodes w*16..+15 sequentially;
// per node: 8 edge-slots x 8 lanes x 16ch, v_dot2_f32_bf16 accumulate, shfl-reduce,
// hc = acc + 0.5*x0 -> bf16 LDS row. Phase 2: hb = relu(hc @ W') via MFMA.
#define DOT16(P, ALO, AHI)                                             \
  {                                                                    \
    uint4 va = *(const uint4*)(P);                                     \
    uint4 vb = *(const uint4*)((P) + 8);                               \
    acc[0] = dot2bf(acc[0], (ALO), va.x);                              \
    acc[1] = dot2bf(acc[1], (AHI), va.x);                              \
    acc[2] = dot2bf(acc[2], (ALO), va.y);                              \
    acc[3] = dot2bf(acc[3], (AHI), va.y);                              \
    acc[4] = dot2bf(acc[4], (ALO), va.z);                              \
    acc[5] = dot2bf(acc[5], (AHI), va.z);                              \
    acc[6] = dot2bf(acc[6], (ALO), va.w);                              \
    acc[7] = dot2bf(acc[7], (AHI), va.w);                              \
    acc[8] = dot2bf(acc[8], (ALO), vb.x);                              \
    acc[9] = dot2bf(acc[9], (AHI), vb.x);                              \
    acc[10] = dot2bf(acc[10], (ALO), vb.y);                            \
    acc[11] = dot2bf(acc[11], (AHI), vb.y);                            \
    acc[12] = dot2bf(acc[12], (ALO), vb.z);                            \
    acc[13] = dot2bf(acc[13], (AHI), vb.z);                            \
    acc[14] = dot2bf(acc[14], (ALO), vb.w);                            \
    acc[15] = dot2bf(acc[15], (AHI), vb.w);                            \
  }

__global__ __launch_bounds__(256) void k_fused(
    const unsigned short* __restrict__ h16, const unsigned short* __restrict__ x016,
    const float* __restrict__ dinv, const int* __restrict__ offs,
    const int2* __restrict__ edata, const unsigned short* __restrict__ Wt16,
    unsigned short* __restrict__ C16, int M) {
  __shared__ unsigned short lds[64 * LW];
  const int tid = threadIdx.x;
  const int lane = tid & 63;
  const int wid = tid >> 6;
  const int m0 = blockIdx.x * 64;
  const int nbase = m0 + wid * 16;

  // preload offs (17 values) and dinv (16) for this wave's nodes
  int offv = 0;
  float dv = 0.f;
  {
    int idx = nbase + lane;
    if (lane < 17) offv = offs[idx > NN ? NN : idx];
    if (lane < 16) dv = dinv[idx >= NN ? NN - 1 : idx];
  }
  const int slot = lane >> 3;
  const int cg = (lane & 7) * 16;
  const unsigned XLO = 0x3F00u, XHI = 0x3F000000u;  // bf16(0.5) masks

#pragma unroll 1
  for (int t = 0; t < 16; ++t) {
    const int node = nbase + t;
    const bool valid = node < M;
    float acc[16];
#pragma unroll
    for (int q = 0; q < 16; ++q) acc[q] = 0.f;
    int b = __shfl(offv, t), e = __shfl(offv, t + 1);
    if (valid) {
      if (slot == 0) {  // self loop
        float dn = __shfl(dv, t);
        unsigned wb = (unsigned)f2bf(0.5f * dn * dn);
        DOT16(h16 + (size_t)node * HID + cg, wb, wb << 16);
      }
      int i = b + slot;
      for (; i + 8 < e; i += 16) {
        int2 e0 = edata[i], e1 = edata[i + 8];
        const unsigned short* p0 = h16 + (size_t)e0.x * HID + cg;
        const unsigned short* p1 = h16 + (size_t)e1.x * HID + cg;
        unsigned y0 = (unsigned)e0.y, y1 = (unsigned)e1.y;
        DOT16(p0, y0 >> 16, y0 & 0xffff0000u);
        DOT16(p1, y1 >> 16, y1 & 0xffff0000u);
      }
      if (i < e) {
        int2 e0 = edata[i];
        unsigned y0 = (unsigned)e0.y;
        DOT16(h16 + (size_t)e0.x * HID + cg, y0 >> 16, y0 & 0xffff0000u);
      }
    }
#pragma unroll
    for (int q = 0; q < 16; ++q) {
      acc[q] += __shfl_xor(acc[q], 8);
      acc[q] += __shfl_xor(acc[q], 16);
      acc[q] += __shfl_xor(acc[q], 32);
    }
    if (slot == 0) {
      unsigned qv[8];
      if (valid) {
        const unsigned short* px = x016 + (size_t)node * HID + cg;
        uint4 xa = *(const uint4*)px, xb = *(const uint4*)(px + 8);
        acc[0] = dot2bf(acc[0], XLO, xa.x);   acc[1] = dot2bf(acc[1], XHI, xa.x);
        acc[2] = dot2bf(acc[2], XLO, xa.y);   acc[3] = dot2bf(acc[3], XHI, xa.y);
        acc[4] = dot2bf(acc[4], XLO, xa.z);   acc[5] = dot2bf(acc[5], XHI, xa.z);
        acc[6] = dot2bf(acc[6], XLO, xa.w);   acc[7] = dot2bf(acc[7], XHI, xa.w);
        acc[8] = dot2bf(acc[8], XLO, xb.x);   acc[9] = dot2bf(acc[9], XHI, xb.x);
        acc[10] = dot2bf(acc[10], XLO, xb.y); acc[11] = dot2bf(acc[11], XHI, xb.y);
        acc[12] = dot2bf(acc[12], XLO, xb.z); acc[13] = dot2bf(acc[13], XHI, xb.z);
        acc[14] = dot2bf(acc[14], XLO, xb.w); acc[15] = dot2bf(acc[15], XHI, xb.w);
#pragma unroll
        for (int q = 0; q < 8; ++q) qv[q] = cvtpk(acc[2 * q], acc[2 * q + 1]);
      } else {
#pragma unroll
        for (int q = 0; q < 8; ++q) qv[q] = 0;
      }
      unsigned short* lrow = &lds[(wid * 16 + t) * LW + cg];
      *(uint4*)(lrow) = *(const uint4*)&qv[0];
      *(uint4*)(lrow + 8) = *(const uint4*)&qv[4];
    }
  }
  __syncthreads();

  // phase 2: GEMM 64x128 (skip folded into W')
  const int rq = (wid >> 1) * 32;
  const int colbase = (wid & 1) * 64;
  const int j = lane & 15, g = lane >> 4;

  bf16x8 bfrag[4][4];
#pragma unroll
  for (int c = 0; c < 4; ++c)
#pragma unroll
    for (int s = 0; s < 4; ++s)
      bfrag[c][s] =
          *(const bf16x8*)(Wt16 + (size_t)(colbase + 16 * c + j) * HID + 32 * s + 8 * g);

  const f32x4 zero = {0.f, 0.f, 0.f, 0.f};
#pragma unroll
  for (int rt = 0; rt < 2; ++rt) {
    bf16x8 af[4];
#pragma unroll
    for (int s = 0; s < 4; ++s)
      af[s] = *(const bf16x8*)&lds[(rq + rt * 16 + j) * LW + 32 * s + 8 * g];
    f32x4 a2[4] = {zero, zero, zero, zero};
#pragma unroll
    for (int s = 0; s < 4; ++s)
#pragma unroll
      for (int c = 0; c < 4; ++c)
        a2[c] = __builtin_amdgcn_mfma_f32_16x16x32_bf16(af[s], bfrag[c][s], a2[c], 0, 0, 0);
#pragma unroll
    for (int i = 0; i < 4; ++i) {
      const int rr = m0 + rq + rt * 16 + 4 * g + i;
      if (rr >= M) continue;
#pragma unroll
      for (int c = 0; c < 4; ++c) {
        const int col = colbase + 16 * c + j;
        C16[(size_t)rr * HID + col] = f2bf(fmaxf(a2[c][i], 0.f));
      }
    }
  }
}
#undef DOT16

// ---------------- fused lin2 + log_softmax via MFMA ----------------
static __global__ __launch_bounds__(256, 3) void k_mlin2(
    const unsigned short* __restrict__ h16, const unsigned short* __restrict__ Wt2,
    const float* __restrict__ b2, float* __restrict__ out) {
  __shared__ unsigned short lds[128 * LW];
  const int tid = threadIdx.x;
  const int lane = tid & 63;
  const int wid = tid >> 6;
  const int j = lane & 15, g = lane >> 4;
  const int m0 = blockIdx.x * 128;

  bf16x8 bfrag[3][4];
#pragma unroll
  for (int c = 0; c < 3; ++c)
#pragma unroll
    for (int s = 0; s < 4; ++s)
      bfrag[c][s] = *(const bf16x8*)(Wt2 + (size_t)(16 * c + j) * HID + 32 * s + 8 * g);

  float bb[3];
#pragma unroll
  for (int c = 0; c < 3; ++c) {
    int col = 16 * c + j;
    bb[c] = (col < OUTC) ? b2[col] : -1e30f;
  }

#pragma unroll 2
  for (int i = 0; i < 8; ++i) {
    int idx = i * 256 + tid;
    int row = idx >> 4, ch = idx & 15;
    int grow = m0 + row;
    if (grow >= NN) grow = NN - 1;
    *(bf16x8*)&lds[row * LW + ch * 8] =
        *(const bf16x8*)(h16 + (size_t)grow * HID + ch * 8);
  }
  __syncthreads();

  const f32x4 zero = {0.f, 0.f, 0.f, 0.f};
#pragma unroll
  for (int rt = 0; rt < 2; ++rt) {
    bf16x8 af[4];
#pragma unroll
    for (int s = 0; s < 4; ++s)
      af[s] = *(const bf16x8*)&lds[(wid * 32 + rt * 16 + j) * LW + 32 * s + 8 * g];
    f32x4 acc[3] = {zero, zero, zero};
#pragma unroll
    for (int s = 0; s < 4; ++s)
#pragma unroll
      for (int c = 0; c < 3; ++c)
        acc[c] = __builtin_amdgcn_mfma_f32_16x16x32_bf16(af[s], bfrag[c][s], acc[c], 0, 0, 0);

#pragma unroll
    for (int i = 0; i < 4; ++i) {
      const int rr = m0 + wid * 32 + rt * 16 + 4 * g + i;
      float z0 = acc[0][i] + bb[0];
      float z1 = acc[1][i] + bb[1];
      float z2 = acc[2][i] + bb[2];
      float m = fmaxf(fmaxf(z0, z1), z2);
      m = fmaxf(m, __shfl_xor(m, 1));
      m = fmaxf(m, __shfl_xor(m, 2));
      m = fmaxf(m, __shfl_xor(m, 4));
      m = fmaxf(m, __shfl_xor(m, 8));
      float sum = __expf(z0 - m) + __expf(z1 - m) + __expf(z2 - m);
      sum += __shfl_xor(sum, 1);
      sum += __shfl_xor(sum, 2);
      sum += __shfl_xor(sum, 4);
      sum += __shfl_xor(sum, 8);
      float ls = m + logf(sum);
      if (rr < NN) {
        out[(size_t)rr * OUTC + j] = z0 - ls;
        out[(size_t)rr * OUTC + 16 + j] = z1 - ls;
        if (j < 8) out[(size_t)rr * OUTC + 32 + j] = z2 - ls;
      }
    }
  }
}

// ---------------- host ----------------
extern "C" void kernel_launch(void* const* d_in, const int* in_sizes, int n_in,
                              void* d_out, int out_size, void* d_ws, size_t ws_size,
                              hipStream_t stream) {
  const float* x  = (const float*)d_in[0];
  const int*   ei = (const int*)d_in[1];
  const float* w1 = (const float*)d_in[2];
  const float* b1 = (const float*)d_in[3];
  const float* cw = (const float*)d_in[4];
  const float* w2 = (const float*)d_in[5];
  const float* b2 = (const float*)d_in[6];
  float* out = (float*)d_out;

  char* ws = (char*)d_ws;
  size_t o = 0;
  auto carve = [&](size_t bytes) {
    void* p = ws + o;
    o = (o + bytes + 255) & ~(size_t)255;
    return p;
  };
  float* dinv   = (float*)carve((size_t)NN * 4);
  int*   offs   = (int*)carve((size_t)(NN + 1) * 4);
  int*   cursor = (int*)carve((size_t)NN * 4);
  int*   bcnt   = (int*)carve((size_t)NBUCK * 4);
  int*   boffs  = (int*)carve((size_t)(NBUCK + 1) * 4);
  int*   bcur   = (int*)carve((size_t)NBUCK * 4);
  int2*  stage  = (int2*)carve((size_t)NE * 8);
  int2*  edata  = (int2*)carve((size_t)NE * 8);
  unsigned short* x016 = (unsigned short*)carve((size_t)NN * HID * 2);
  unsigned short* hbA  = (unsigned short*)carve((size_t)NN * HID * 2);
  unsigned short* hbB  = (unsigned short*)carve((size_t)NN * HID * 2);
  unsigned short* wt1  = (unsigned short*)carve((size_t)INCH * HID * 2);
  unsigned short* wtl  = (unsigned short*)carve((size_t)NLAYERS * HID * HID * 2);
  unsigned short* wt2  = (unsigned short*)carve((size_t)48 * HID * 2);
  (void)ws_size; (void)in_sizes; (void)n_in; (void)out_size;

  const int TB = 256;
  const int gEB = (NE + EPB - 1) / EPB;  // 391

  k_zerob<<<(NBUCK + 255) / 256, TB, 0, stream>>>(bcnt);
  k_bhist<<<gEB, TB, 0, stream>>>(ei, bcnt);
  k_bscan<<<1, 512, 0, stream>>>(bcnt, boffs, bcur, offs);
  k_sortA<<<gEB, TB, 0, stream>>>(ei, bcur, stage);
  k_degs<<<NBUCK, TB, 0, stream>>>(stage, boffs, offs, dinv, cursor);
  k_passB2<<<NBUCK, TB, 0, stream>>>(stage, boffs, offs, dinv, cursor, edata);

  k_cvtw<<<(INCH * HID + 255) / 256, 256, 0, stream>>>(w1, wt1, INCH);
  k_cvtw8<<<(NLAYERS * HID * HID + 255) / 256, 256, 0, stream>>>(cw, wtl);
  k_cvtw2<<<(48 * HID + 255) / 256, 256, 0, stream>>>(w2, wt2);

  k_lin1<<<(NN + 127) / 128, 256, 0, stream>>>(x, wt1, b1, x016, NN);

  const int gF = (NN + 63) / 64;  // 1563
  const unsigned short* hin = x016;
  unsigned short* hout = hbA;
  for (int l = 0; l < NLAYERS; ++l) {
    k_fused<<<gF, 256, 0, stream>>>(hin, x016, dinv, offs, edata,
                                    wtl + (size_t)l * HID * HID, hout, NN);
    hin = hout;
    hout = (hout == hbA) ? hbB : hbA;
  }
  k_mlin2<<<(NN + 127) / 128, 256, 0, stream>>>(hin, wt2, b2, out);
}

// Round 12
// 772.465 us; speedup vs baseline: 1.3162x; 1.3162x over previous
//
#include <hip/hip_runtime.h>
#include <math.h>

#define NN 100000
#define NE 1600000
#define HID 128
#define INCH 256
#define OUTC 40
#define NLAYERS 8
#define NBUCK 391   // ceil(NN/256)
#define EPB 4096
#define CAP 6144
#define LW 136      // LDS row stride in ushorts (272 B)

typedef __attribute__((ext_vector_type(8))) short bf16x8;
typedef __attribute__((ext_vector_type(4))) float f32x4;

static __device__ inline unsigned short f2bf(float f) {
  unsigned u = __float_as_uint(f);
  unsigned r = (u + 0x7fff + ((u >> 16) & 1)) >> 16;
  return (unsigned short)r;
}
static __device__ inline float bflo(unsigned u) { return __uint_as_float(u << 16); }
static __device__ inline float bfhi(unsigned u) { return __uint_as_float(u & 0xffff0000u); }

// ---------------- preprocessing (atomic-light counting sort) ----------------

static __global__ void k_zerob(int* __restrict__ bcnt) {
  int i = blockIdx.x * 256 + threadIdx.x;
  if (i < NBUCK) bcnt[i] = 0;
}

static __global__ __launch_bounds__(256) void k_bhist(const int* __restrict__ ei,
                                                      int* __restrict__ bcnt) {
  __shared__ int lh[NBUCK + 1];
  int t = threadIdx.x;
  for (int i = t; i <= NBUCK; i += 256) lh[i] = 0;
  __syncthreads();
  int e0 = blockIdx.x * EPB;
  for (int k = t; k < EPB; k += 256) {
    int e = e0 + k;
    if (e < NE) atomicAdd(&lh[ei[NE + e] >> 8], 1);
  }
  __syncthreads();
  for (int i = t; i < NBUCK; i += 256)
    if (lh[i]) atomicAdd(&bcnt[i], lh[i]);
}

static __global__ void k_bscan(const int* __restrict__ bcnt, int* __restrict__ boffs,
                               int* __restrict__ bcur, int* __restrict__ offs) {
  __shared__ int sd[512];
  int t = threadIdx.x;
  sd[t] = (t < NBUCK) ? bcnt[t] : 0;
  __syncthreads();
  for (int d = 1; d < 512; d <<= 1) {
    int v = (t >= d) ? sd[t - d] : 0;
    __syncthreads();
    sd[t] += v;
    __syncthreads();
  }
  if (t < NBUCK) {
    boffs[t + 1] = sd[t];
    bcur[t] = sd[t] - bcnt[t];
  }
  if (t == 0) { boffs[0] = 0; offs[NN] = NE; }
}

static __global__ __launch_bounds__(256) void k_sortA(const int* __restrict__ ei,
                                                      int* __restrict__ bcur,
                                                      int2* __restrict__ stage) {
  __shared__ int lsrc[EPB], ldst[EPB];
  __shared__ int lh[NBUCK + 1], lbase[NBUCK + 1], lcur[NBUCK + 1];
  int t = threadIdx.x;
  int e0 = blockIdx.x * EPB;
  for (int k = t; k < EPB; k += 256) {
    int e = e0 + k;
    lsrc[k] = (e < NE) ? ei[e] : -1;
    ldst[k] = (e < NE) ? ei[NE + e] : -1;
  }
  for (int i = t; i <= NBUCK; i += 256) lh[i] = 0;
  __syncthreads();
  for (int k = t; k < EPB; k += 256)
    if (ldst[k] >= 0) atomicAdd(&lh[ldst[k] >> 8], 1);
  __syncthreads();
  for (int i = t; i < NBUCK; i += 256) {
    int c = lh[i];
    lbase[i] = c ? atomicAdd(&bcur[i], c) : 0;
    lcur[i] = 0;
  }
  __syncthreads();
  for (int k = t; k < EPB; k += 256) {
    int d = ldst[k];
    if (d >= 0) {
      int bu = d >> 8;
      int r = atomicAdd(&lcur[bu], 1);
      stage[lbase[bu] + r] = make_int2(lsrc[k], d);
    }
  }
}

static __global__ __launch_bounds__(256) void k_degs(
    const int2* __restrict__ stage, const int* __restrict__ boffs,
    int* __restrict__ offs, float* __restrict__ dinv, int* __restrict__ cursor) {
  __shared__ int lcnt[256];
  __shared__ int sd[256];
  int b = blockIdx.x, t = threadIdx.x;
  int sb = boffs[b], se = boffs[b + 1];
  int cntb = se - sb;
  int nb0 = b << 8;
  lcnt[t] = 0;
  __syncthreads();
  for (int k = t; k < cntb; k += 256) atomicAdd(&lcnt[stage[sb + k].y - nb0], 1);
  __syncthreads();
  int v = lcnt[t];
  sd[t] = v;
  __syncthreads();
  for (int d = 1; d < 256; d <<= 1) {
    int u = (t >= d) ? sd[t - d] : 0;
    __syncthreads();
    sd[t] += u;
    __syncthreads();
  }
  int n = nb0 + t;
  if (n < NN) {
    int o = sb + sd[t] - v;
    offs[n] = o;
    cursor[n] = o;
    dinv[n] = rsqrtf((float)(v + 1));
  }
}

static __global__ __launch_bounds__(256) void k_passB2(
    const int2* __restrict__ stage, const int* __restrict__ boffs,
    const int* __restrict__ offs, const float* __restrict__ dinv,
    int* __restrict__ cursor, int2* __restrict__ edata) {
  __shared__ int2 lbuf[CAP];
  __shared__ int lcur[256];
  int b = blockIdx.x, t = threadIdx.x;
  int sb = boffs[b], se = boffs[b + 1];
  int cntb = se - sb;
  int nb0 = b << 8;
  if (cntb <= CAP) {
    if (nb0 + t < NN) lcur[t] = offs[nb0 + t] - sb;
    __syncthreads();
    for (int k = t; k < cntb; k += 256) {
      int2 sd_ = stage[sb + k];
      float w = dinv[sd_.x] * dinv[sd_.y];
      int p = atomicAdd(&lcur[sd_.y - nb0], 1);
      lbuf[p] = make_int2(sd_.x, __float_as_int(w));
    }
    __syncthreads();
    for (int k = t; k < cntb; k += 256) edata[sb + k] = lbuf[k];
  } else {
    for (int k = t; k < cntb; k += 256) {
      int2 sd_ = stage[sb + k];
      float w = dinv[sd_.x] * dinv[sd_.y];
      int p = atomicAdd(&cursor[sd_.y], 1);
      edata[p] = make_int2(sd_.x, __float_as_int(w));
    }
  }
}

// ---------------- weight conversion ----------------
static __global__ void k_cvtw(const float* __restrict__ W, unsigned short* __restrict__ Wt,
                              int K) {
  int idx = blockIdx.x * 256 + threadIdx.x;
  if (idx < K * HID) {
    int k = idx >> 7, n = idx & 127;
    Wt[(size_t)n * K + k] = f2bf(W[idx]);
  }
}

// Folded layer weights: W'_l = beta_l * W_l + (1-beta_l) * I, transposed [n][k]
static __global__ void k_cvtw8(const float* __restrict__ W, unsigned short* __restrict__ Wt) {
  int idx = blockIdx.x * 256 + threadIdx.x;
  if (idx < NLAYERS * HID * HID) {
    int l = idx >> 14, rem = idx & 16383;
    int k = rem >> 7, n = rem & 127;
    float beta = logf(1.0f / (float)(l + 1) + 1.0f);
    float v = beta * W[idx];
    if (k == n) v += 1.0f - beta;
    Wt[(size_t)l * HID * HID + n * HID + k] = f2bf(v);
  }
}

static __global__ void k_cvtw2(const float* __restrict__ W2, unsigned short* __restrict__ Wt2) {
  int idx = blockIdx.x * 256 + threadIdx.x;
  if (idx < 48 * HID) {
    int n = idx >> 7, k = idx & 127;
    Wt2[idx] = (n < OUTC) ? f2bf(W2[(size_t)k * OUTC + n]) : 0;
  }
}

// ---------------- lin1: C16[M x 128] = bf16(relu(A32[M x 256] @ W + bias)) ----------------
__global__ __launch_bounds__(256, 3) void k_lin1(
    const float* __restrict__ A32, const unsigned short* __restrict__ Wt16,
    const float* __restrict__ bias, unsigned short* __restrict__ C16, int M) {
  __shared__ unsigned short lds[128 * LW];
  const int tid = threadIdx.x;
  const int lane = tid & 63;
  const int wid = tid >> 6;
  const int j = lane & 15, g = lane >> 4;
  const int rowhalf = (wid >> 1) * 64;
  const int colbase = (wid & 1) * 64;
  const int m0 = blockIdx.x * 128;

  f32x4 acc[4][4];
  const f32x4 zero = {0.f, 0.f, 0.f, 0.f};
#pragma unroll
  for (int rt = 0; rt < 4; ++rt)
#pragma unroll
    for (int c = 0; c < 4; ++c) acc[rt][c] = zero;

#pragma unroll 1
  for (int kc = 0; kc < 2; ++kc) {
    bf16x8 bfrag[4][4];
#pragma unroll
    for (int c = 0; c < 4; ++c)
#pragma unroll
      for (int s = 0; s < 4; ++s)
        bfrag[c][s] = *(const bf16x8*)(Wt16 + (size_t)(colbase + 16 * c + j) * INCH +
                                       kc * 128 + 32 * s + 8 * g);
    __syncthreads();
#pragma unroll 2
    for (int i = 0; i < 8; ++i) {
      int idx = i * 256 + tid;
      int row = idx >> 4, ch = idx & 15;
      int grow = m0 + row;
      if (grow >= M) grow = M - 1;
      const float* p = A32 + (size_t)grow * INCH + kc * 128 + ch * 8;
      float4 u0 = *(const float4*)p;
      float4 u1 = *(const float4*)(p + 4);
      bf16x8 v;
      v[0] = (short)f2bf(u0.x); v[1] = (short)f2bf(u0.y);
      v[2] = (short)f2bf(u0.z); v[3] = (short)f2bf(u0.w);
      v[4] = (short)f2bf(u1.x); v[5] = (short)f2bf(u1.y);
      v[6] = (short)f2bf(u1.z); v[7] = (short)f2bf(u1.w);
      *(bf16x8*)&lds[row * LW + ch * 8] = v;
    }
    __syncthreads();
#pragma unroll
    for (int rt = 0; rt < 4; ++rt) {
      bf16x8 af[4];
#pragma unroll
      for (int s = 0; s < 4; ++s)
        af[s] = *(const bf16x8*)&lds[(rowhalf + rt * 16 + j) * LW + 32 * s + 8 * g];
#pragma unroll
      for (int s = 0; s < 4; ++s)
#pragma unroll
        for (int c = 0; c < 4; ++c)
          acc[rt][c] =
              __builtin_amdgcn_mfma_f32_16x16x32_bf16(af[s], bfrag[c][s], acc[rt][c], 0, 0, 0);
    }
  }

#pragma unroll
  for (int rt = 0; rt < 4; ++rt)
#pragma unroll
    for (int i = 0; i < 4; ++i) {
      const int rr = m0 + rowhalf + rt * 16 + 4 * g + i;
      if (rr >= M) continue;
#pragma unroll
      for (int c = 0; c < 4; ++c) {
        const int col = colbase + 16 * c + j;
        float z = fmaxf(acc[rt][c][i] + bias[col], 0.f);
        C16[(size_t)rr * HID + col] = f2bf(z);
      }
    }
}

// ---------------- fused layer: agg (gather) + GEMM ----------------
// Block = 64 nodes. Phase 1: hc = 0.5*(A_hat@h)+0.5*x0 -> LDS bf16 tile.
//   Thread per node-quarter (4 lanes x 32 ch), edata software-pipelined.
// Phase 2: hb = relu(hc @ W') via MFMA (skip folded into W'), tile 64x128.
#define ACC8(V, O, W)                                       \
  acc[(O) + 0] = fmaf((W), bflo((V).x), acc[(O) + 0]);      \
  acc[(O) + 1] = fmaf((W), bfhi((V).x), acc[(O) + 1]);      \
  acc[(O) + 2] = fmaf((W), bflo((V).y), acc[(O) + 2]);      \
  acc[(O) + 3] = fmaf((W), bfhi((V).y), acc[(O) + 3]);      \
  acc[(O) + 4] = fmaf((W), bflo((V).z), acc[(O) + 4]);      \
  acc[(O) + 5] = fmaf((W), bfhi((V).z), acc[(O) + 5]);      \
  acc[(O) + 6] = fmaf((W), bflo((V).w), acc[(O) + 6]);      \
  acc[(O) + 7] = fmaf((W), bfhi((V).w), acc[(O) + 7]);

#define ACCROW(V0, V1, V2, V3, W) \
  ACC8(V0, 0, W) ACC8(V1, 8, W) ACC8(V2, 16, W) ACC8(V3, 24, W)

__global__ __launch_bounds__(256) void k_fused(
    const unsigned short* __restrict__ h16, const unsigned short* __restrict__ x016,
    const float* __restrict__ dinv, const int* __restrict__ offs,
    const int2* __restrict__ edata, const unsigned short* __restrict__ Wt16,
    unsigned short* __restrict__ C16, int M) {
  __shared__ unsigned short lds[64 * LW];
  const int tid = threadIdx.x;
  const int m0 = blockIdx.x * 64;
  const int node = m0 + (tid >> 2);
  const int cq = (tid & 3) * 32;

  float acc[32];
#pragma unroll
  for (int q = 0; q < 32; ++q) acc[q] = 0.f;

  unsigned short q16[32];
  if (node < M) {
    int b = offs[node], e = offs[node + 1];
    float dn = dinv[node];
    {  // self loop
      const unsigned short* p = h16 + (size_t)node * HID + cq;
      uint4 s0 = *(const uint4*)p, s1 = *(const uint4*)(p + 8);
      uint4 s2 = *(const uint4*)(p + 16), s3 = *(const uint4*)(p + 24);
      float w = dn * dn;
      ACCROW(s0, s1, s2, s3, w)
    }
    int i = b;
    int2 n0, n1;
    if (i + 3 < e) { n0 = edata[i]; n1 = edata[i + 1]; }
    // steady: 2 edges/iter, next pair's edata prefetched one iter ahead
    for (; i + 3 < e; i += 2) {
      int2 c0 = n0, c1 = n1;
      n0 = edata[i + 2];
      n1 = edata[i + 3];
      const unsigned short* p0 = h16 + (size_t)c0.x * HID + cq;
      const unsigned short* p1 = h16 + (size_t)c1.x * HID + cq;
      uint4 r0 = *(const uint4*)p0, r1 = *(const uint4*)(p0 + 8);
      uint4 r2 = *(const uint4*)(p0 + 16), r3 = *(const uint4*)(p0 + 24);
      uint4 r4 = *(const uint4*)p1, r5 = *(const uint4*)(p1 + 8);
      uint4 r6 = *(const uint4*)(p1 + 16), r7 = *(const uint4*)(p1 + 24);
      float w0 = __int_as_float(c0.y), w1 = __int_as_float(c1.y);
      ACCROW(r0, r1, r2, r3, w0)
      ACCROW(r4, r5, r6, r7, w1)
    }
    for (; i < e; ++i) {
      int2 e0 = edata[i];
      const unsigned short* p0 = h16 + (size_t)e0.x * HID + cq;
      uint4 r0 = *(const uint4*)p0, r1 = *(const uint4*)(p0 + 8);
      uint4 r2 = *(const uint4*)(p0 + 16), r3 = *(const uint4*)(p0 + 24);
      float w0 = __int_as_float(e0.y);
      ACCROW(r0, r1, r2, r3, w0)
    }
    // hc = 0.5*acc + 0.5*x0 -> bf16
    const unsigned short* px = x016 + (size_t)node * HID + cq;
    uint4 xa = *(const uint4*)px, xb = *(const uint4*)(px + 8);
    uint4 xc = *(const uint4*)(px + 16), xd = *(const uint4*)(px + 24);
    float xo[32];
#define UNP8(V, O)                                                     \
    xo[(O) + 0] = bflo((V).x); xo[(O) + 1] = bfhi((V).x);              \
    xo[(O) + 2] = bflo((V).y); xo[(O) + 3] = bfhi((V).y);              \
    xo[(O) + 4] = bflo((V).z); xo[(O) + 5] = bfhi((V).z);              \
    xo[(O) + 6] = bflo((V).w); xo[(O) + 7] = bfhi((V).w);
    UNP8(xa, 0) UNP8(xb, 8) UNP8(xc, 16) UNP8(xd, 24)
#undef UNP8
#pragma unroll
    for (int q = 0; q < 32; ++q) q16[q] = f2bf(0.5f * acc[q] + 0.5f * xo[q]);
  } else {
#pragma unroll
    for (int q = 0; q < 32; ++q) q16[q] = 0;
  }
  {
    unsigned short* lrow = &lds[(tid >> 2) * LW + cq];
    *(uint4*)(lrow) = *(const uint4*)&q16[0];
    *(uint4*)(lrow + 8) = *(const uint4*)&q16[8];
    *(uint4*)(lrow + 16) = *(const uint4*)&q16[16];
    *(uint4*)(lrow + 24) = *(const uint4*)&q16[24];
  }
  __syncthreads();

  // phase 2: GEMM 64x128
  const int lane = tid & 63;
  const int wid = tid >> 6;
  const int rq = (wid >> 1) * 32;
  const int colbase = (wid & 1) * 64;
  const int j = lane & 15, g = lane >> 4;

  bf16x8 bfrag[4][4];
#pragma unroll
  for (int c = 0; c < 4; ++c)
#pragma unroll
    for (int s = 0; s < 4; ++s)
      bfrag[c][s] =
          *(const bf16x8*)(Wt16 + (size_t)(colbase + 16 * c + j) * HID + 32 * s + 8 * g);

  const f32x4 zero = {0.f, 0.f, 0.f, 0.f};
#pragma unroll
  for (int rt = 0; rt < 2; ++rt) {
    bf16x8 af[4];
#pragma unroll
    for (int s = 0; s < 4; ++s)
      af[s] = *(const bf16x8*)&lds[(rq + rt * 16 + j) * LW + 32 * s + 8 * g];
    f32x4 a2[4] = {zero, zero, zero, zero};
#pragma unroll
    for (int s = 0; s < 4; ++s)
#pragma unroll
      for (int c = 0; c < 4; ++c)
        a2[c] = __builtin_amdgcn_mfma_f32_16x16x32_bf16(af[s], bfrag[c][s], a2[c], 0, 0, 0);
#pragma unroll
    for (int i = 0; i < 4; ++i) {
      const int rr = m0 + rq + rt * 16 + 4 * g + i;
      if (rr >= M) continue;
#pragma unroll
      for (int c = 0; c < 4; ++c) {
        const int col = colbase + 16 * c + j;
        C16[(size_t)rr * HID + col] = f2bf(fmaxf(a2[c][i], 0.f));
      }
    }
  }
}

// ---------------- fused lin2 + log_softmax via MFMA ----------------
static __global__ __launch_bounds__(256, 3) void k_mlin2(
    const unsigned short* __restrict__ h16, const unsigned short* __restrict__ Wt2,
    const float* __restrict__ b2, float* __restrict__ out) {
  __shared__ unsigned short lds[128 * LW];
  const int tid = threadIdx.x;
  const int lane = tid & 63;
  const int wid = tid >> 6;
  const int j = lane & 15, g = lane >> 4;
  const int m0 = blockIdx.x * 128;

  bf16x8 bfrag[3][4];
#pragma unroll
  for (int c = 0; c < 3; ++c)
#pragma unroll
    for (int s = 0; s < 4; ++s)
      bfrag[c][s] = *(const bf16x8*)(Wt2 + (size_t)(16 * c + j) * HID + 32 * s + 8 * g);

  float bb[3];
#pragma unroll
  for (int c = 0; c < 3; ++c) {
    int col = 16 * c + j;
    bb[c] = (col < OUTC) ? b2[col] : -1e30f;
  }

#pragma unroll 2
  for (int i = 0; i < 8; ++i) {
    int idx = i * 256 + tid;
    int row = idx >> 4, ch = idx & 15;
    int grow = m0 + row;
    if (grow >= NN) grow = NN - 1;
    *(bf16x8*)&lds[row * LW + ch * 8] =
        *(const bf16x8*)(h16 + (size_t)grow * HID + ch * 8);
  }
  __syncthreads();

  const f32x4 zero = {0.f, 0.f, 0.f, 0.f};
#pragma unroll
  for (int rt = 0; rt < 2; ++rt) {
    bf16x8 af[4];
#pragma unroll
    for (int s = 0; s < 4; ++s)
      af[s] = *(const bf16x8*)&lds[(wid * 32 + rt * 16 + j) * LW + 32 * s + 8 * g];
    f32x4 acc[3] = {zero, zero, zero};
#pragma unroll
    for (int s = 0; s < 4; ++s)
#pragma unroll
      for (int c = 0; c < 3; ++c)
        acc[c] = __builtin_amdgcn_mfma_f32_16x16x32_bf16(af[s], bfrag[c][s], acc[c], 0, 0, 0);

#pragma unroll
    for (int i = 0; i < 4; ++i) {
      const int rr = m0 + wid * 32 + rt * 16 + 4 * g + i;
      float z0 = acc[0][i] + bb[0];
      float z1 = acc[1][i] + bb[1];
      float z2 = acc[2][i] + bb[2];
      float m = fmaxf(fmaxf(z0, z1), z2);
      m = fmaxf(m, __shfl_xor(m, 1));
      m = fmaxf(m, __shfl_xor(m, 2));
      m = fmaxf(m, __shfl_xor(m, 4));
      m = fmaxf(m, __shfl_xor(m, 8));
      float sum = __expf(z0 - m) + __expf(z1 - m) + __expf(z2 - m);
      sum += __shfl_xor(sum, 1);
      sum += __shfl_xor(sum, 2);
      sum += __shfl_xor(sum, 4);
      sum += __shfl_xor(sum, 8);
      float ls = m + logf(sum);
      if (rr < NN) {
        out[(size_t)rr * OUTC + j] = z0 - ls;
        out[(size_t)rr * OUTC + 16 + j] = z1 - ls;
        if (j < 8) out[(size_t)rr * OUTC + 32 + j] = z2 - ls;
      }
    }
  }
}

// ---------------- host ----------------
extern "C" void kernel_launch(void* const* d_in, const int* in_sizes, int n_in,
                              void* d_out, int out_size, void* d_ws, size_t ws_size,
                              hipStream_t stream) {
  const float* x  = (const float*)d_in[0];
  const int*   ei = (const int*)d_in[1];
  const float* w1 = (const float*)d_in[2];
  const float* b1 = (const float*)d_in[3];
  const float* cw = (const float*)d_in[4];
  const float* w2 = (const float*)d_in[5];
  const float* b2 = (const float*)d_in[6];
  float* out = (float*)d_out;

  char* ws = (char*)d_ws;
  size_t o = 0;
  auto carve = [&](size_t bytes) {
    void* p = ws + o;
    o = (o + bytes + 255) & ~(size_t)255;
    return p;
  };
  float* dinv   = (float*)carve((size_t)NN * 4);
  int*   offs   = (int*)carve((size_t)(NN + 1) * 4);
  int*   cursor = (int*)carve((size_t)NN * 4);
  int*   bcnt   = (int*)carve((size_t)NBUCK * 4);
  int*   boffs  = (int*)carve((size_t)(NBUCK + 1) * 4);
  int*   bcur   = (int*)carve((size_t)NBUCK * 4);
  int2*  stage  = (int2*)carve((size_t)NE * 8);
  int2*  edata  = (int2*)carve((size_t)NE * 8);
  unsigned short* x016 = (unsigned short*)carve((size_t)NN * HID * 2);
  unsigned short* hbA  = (unsigned short*)carve((size_t)NN * HID * 2);
  unsigned short* hbB  = (unsigned short*)carve((size_t)NN * HID * 2);
  unsigned short* wt1  = (unsigned short*)carve((size_t)INCH * HID * 2);
  unsigned short* wtl  = (unsigned short*)carve((size_t)NLAYERS * HID * HID * 2);
  unsigned short* wt2  = (unsigned short*)carve((size_t)48 * HID * 2);
  (void)ws_size; (void)in_sizes; (void)n_in; (void)out_size;

  const int TB = 256;
  const int gEB = (NE + EPB - 1) / EPB;  // 391

  k_zerob<<<(NBUCK + 255) / 256, TB, 0, stream>>>(bcnt);
  k_bhist<<<gEB, TB, 0, stream>>>(ei, bcnt);
  k_bscan<<<1, 512, 0, stream>>>(bcnt, boffs, bcur, offs);
  k_sortA<<<gEB, TB, 0, stream>>>(ei, bcur, stage);
  k_degs<<<NBUCK, TB, 0, stream>>>(stage, boffs, offs, dinv, cursor);
  k_passB2<<<NBUCK, TB, 0, stream>>>(stage, boffs, offs, dinv, cursor, edata);

  k_cvtw<<<(INCH * HID + 255) / 256, 256, 0, stream>>>(w1, wt1, INCH);
  k_cvtw8<<<(NLAYERS * HID * HID + 255) / 256, 256, 0, stream>>>(cw, wtl);
  k_cvtw2<<<(48 * HID + 255) / 256, 256, 0, stream>>>(w2, wt2);

  k_lin1<<<(NN + 127) / 128, 256, 0, stream>>>(x, wt1, b1, x016, NN);

  const int gF = (NN + 63) / 64;  // 1563
  const unsigned short* hin = x016;
  unsigned short* hout = hbA;
  for (int l = 0; l < NLAYERS; ++l) {
    k_fused<<<gF, 256, 0, stream>>>(hin, x016, dinv, offs, edata,
                                    wtl + (size_t)l * HID * HID, hout, NN);
    hin = hout;
    hout = (hout == hbA) ? hbB : hbA;
  }
  k_mlin2<<<(NN + 127) / 128, 256, 0, stream>>>(hin, wt2, b2, out);
}

// Round 13
// 764.240 us; speedup vs baseline: 1.3304x; 1.0108x over previous
//
#include <hip/hip_runtime.h>
#include <math.h>

#define NN 100000
#define NE 1600000
#define HID 128
#define INCH 256
#define OUTC 40
#define NLAYERS 8
#define NBUCK 391   // ceil(NN/256)
#define EPB 4096
#define CAP 6144
#define LW 136      // LDS row stride in ushorts (272 B)

typedef __attribute__((ext_vector_type(8))) short bf16x8;
typedef __attribute__((ext_vector_type(4))) float f32x4;

static __device__ inline unsigned short f2bf(float f) {
  unsigned u = __float_as_uint(f);
  unsigned r = (u + 0x7fff + ((u >> 16) & 1)) >> 16;
  return (unsigned short)r;
}
static __device__ inline float bflo(unsigned u) { return __uint_as_float(u << 16); }
static __device__ inline float bfhi(unsigned u) { return __uint_as_float(u & 0xffff0000u); }

// ---------------- preprocessing (atomic-light counting sort + degree perm) ----------------

static __global__ void k_zerob(int* __restrict__ bcnt, int* __restrict__ dbin) {
  int i = blockIdx.x * 256 + threadIdx.x;
  if (i < NBUCK) bcnt[i] = 0;
  if (i < 64) dbin[i] = 0;
}

static __global__ __launch_bounds__(256) void k_bhist(const int* __restrict__ ei,
                                                      int* __restrict__ bcnt) {
  __shared__ int lh[NBUCK + 1];
  int t = threadIdx.x;
  for (int i = t; i <= NBUCK; i += 256) lh[i] = 0;
  __syncthreads();
  int e0 = blockIdx.x * EPB;
  for (int k = t; k < EPB; k += 256) {
    int e = e0 + k;
    if (e < NE) atomicAdd(&lh[ei[NE + e] >> 8], 1);
  }
  __syncthreads();
  for (int i = t; i < NBUCK; i += 256)
    if (lh[i]) atomicAdd(&bcnt[i], lh[i]);
}

static __global__ void k_bscan(const int* __restrict__ bcnt, int* __restrict__ boffs,
                               int* __restrict__ bcur, int* __restrict__ offs) {
  __shared__ int sd[512];
  int t = threadIdx.x;
  sd[t] = (t < NBUCK) ? bcnt[t] : 0;
  __syncthreads();
  for (int d = 1; d < 512; d <<= 1) {
    int v = (t >= d) ? sd[t - d] : 0;
    __syncthreads();
    sd[t] += v;
    __syncthreads();
  }
  if (t < NBUCK) {
    boffs[t + 1] = sd[t];
    bcur[t] = sd[t] - bcnt[t];
  }
  if (t == 0) { boffs[0] = 0; offs[NN] = NE; }
}

static __global__ __launch_bounds__(256) void k_sortA(const int* __restrict__ ei,
                                                      int* __restrict__ bcur,
                                                      int2* __restrict__ stage) {
  __shared__ int lsrc[EPB], ldst[EPB];
  __shared__ int lh[NBUCK + 1], lbase[NBUCK + 1], lcur[NBUCK + 1];
  int t = threadIdx.x;
  int e0 = blockIdx.x * EPB;
  for (int k = t; k < EPB; k += 256) {
    int e = e0 + k;
    lsrc[k] = (e < NE) ? ei[e] : -1;
    ldst[k] = (e < NE) ? ei[NE + e] : -1;
  }
  for (int i = t; i <= NBUCK; i += 256) lh[i] = 0;
  __syncthreads();
  for (int k = t; k < EPB; k += 256)
    if (ldst[k] >= 0) atomicAdd(&lh[ldst[k] >> 8], 1);
  __syncthreads();
  for (int i = t; i < NBUCK; i += 256) {
    int c = lh[i];
    lbase[i] = c ? atomicAdd(&bcur[i], c) : 0;
    lcur[i] = 0;
  }
  __syncthreads();
  for (int k = t; k < EPB; k += 256) {
    int d = ldst[k];
    if (d >= 0) {
      int bu = d >> 8;
      int r = atomicAdd(&lcur[bu], 1);
      stage[lbase[bu] + r] = make_int2(lsrc[k], d);
    }
  }
}

static __global__ __launch_bounds__(256) void k_degs(
    const int2* __restrict__ stage, const int* __restrict__ boffs,
    int* __restrict__ offs, float* __restrict__ dinv, int* __restrict__ cursor,
    int* __restrict__ deg, int* __restrict__ dbin) {
  __shared__ int lcnt[256];
  __shared__ int sd[256];
  __shared__ int lhd[64];
  int b = blockIdx.x, t = threadIdx.x;
  int sb = boffs[b], se = boffs[b + 1];
  int cntb = se - sb;
  int nb0 = b << 8;
  lcnt[t] = 0;
  if (t < 64) lhd[t] = 0;
  __syncthreads();
  for (int k = t; k < cntb; k += 256) atomicAdd(&lcnt[stage[sb + k].y - nb0], 1);
  __syncthreads();
  int v = lcnt[t];
  sd[t] = v;
  __syncthreads();
  for (int d = 1; d < 256; d <<= 1) {
    int u = (t >= d) ? sd[t - d] : 0;
    __syncthreads();
    sd[t] += u;
    __syncthreads();
  }
  int n = nb0 + t;
  if (n < NN) {
    int o = sb + sd[t] - v;
    offs[n] = o;
    cursor[n] = o;
    dinv[n] = rsqrtf((float)(v + 1));
    deg[n] = v;
    int bin = 63 - (v > 63 ? 63 : v);  // heavy nodes first
    atomicAdd(&lhd[bin], 1);
  }
  __syncthreads();
  if (t < 64 && lhd[t]) atomicAdd(&dbin[t], lhd[t]);
}

static __global__ void k_dscan(const int* __restrict__ dbin, int* __restrict__ dcur) {
  __shared__ int sd[64];
  int t = threadIdx.x;
  sd[t] = dbin[t];
  __syncthreads();
  if (t == 0) {
    int a = 0;
    for (int i = 0; i < 64; ++i) { int v = sd[i]; sd[i] = a; a += v; }
  }
  __syncthreads();
  dcur[t] = sd[t];
}

static __global__ __launch_bounds__(256) void k_perm(const int* __restrict__ deg,
                                                     int* __restrict__ dcur,
                                                     int* __restrict__ perm,
                                                     int* __restrict__ inv) {
  __shared__ int lh[64], lbase[64], lcur[64];
  int t = threadIdx.x;
  int n = blockIdx.x * 256 + t;
  if (t < 64) { lh[t] = 0; lcur[t] = 0; }
  __syncthreads();
  int bin = 0;
  if (n < NN) {
    int d = deg[n];
    bin = 63 - (d > 63 ? 63 : d);
    atomicAdd(&lh[bin], 1);
  }
  __syncthreads();
  if (t < 64) lbase[t] = lh[t] ? atomicAdd(&dcur[t], lh[t]) : 0;
  __syncthreads();
  if (n < NN) {
    int r = atomicAdd(&lcur[bin], 1);
    int pos = lbase[bin] + r;
    perm[pos] = n;
    inv[n] = pos;
  }
}

// edata.x = inv[src] (permuted-space source index)
static __global__ __launch_bounds__(256) void k_passB2(
    const int2* __restrict__ stage, const int* __restrict__ boffs,
    const int* __restrict__ offs, const float* __restrict__ dinv,
    const int* __restrict__ inv, int* __restrict__ cursor, int2* __restrict__ edata) {
  __shared__ int2 lbuf[CAP];
  __shared__ int lcur[256];
  int b = blockIdx.x, t = threadIdx.x;
  int sb = boffs[b], se = boffs[b + 1];
  int cntb = se - sb;
  int nb0 = b << 8;
  if (cntb <= CAP) {
    if (nb0 + t < NN) lcur[t] = offs[nb0 + t] - sb;
    __syncthreads();
    for (int k = t; k < cntb; k += 256) {
      int2 sd_ = stage[sb + k];
      float w = dinv[sd_.x] * dinv[sd_.y];
      int p = atomicAdd(&lcur[sd_.y - nb0], 1);
      lbuf[p] = make_int2(inv[sd_.x], __float_as_int(w));
    }
    __syncthreads();
    for (int k = t; k < cntb; k += 256) edata[sb + k] = lbuf[k];
  } else {
    for (int k = t; k < cntb; k += 256) {
      int2 sd_ = stage[sb + k];
      float w = dinv[sd_.x] * dinv[sd_.y];
      int p = atomicAdd(&cursor[sd_.y], 1);
      edata[p] = make_int2(inv[sd_.x], __float_as_int(w));
    }
  }
}

// ---------------- weight conversion ----------------
static __global__ void k_cvtw(const float* __restrict__ W, unsigned short* __restrict__ Wt,
                              int K) {
  int idx = blockIdx.x * 256 + threadIdx.x;
  if (idx < K * HID) {
    int k = idx >> 7, n = idx & 127;
    Wt[(size_t)n * K + k] = f2bf(W[idx]);
  }
}

// Folded layer weights: W'_l = beta_l * W_l + (1-beta_l) * I, transposed [n][k]
static __global__ void k_cvtw8(const float* __restrict__ W, unsigned short* __restrict__ Wt) {
  int idx = blockIdx.x * 256 + threadIdx.x;
  if (idx < NLAYERS * HID * HID) {
    int l = idx >> 14, rem = idx & 16383;
    int k = rem >> 7, n = rem & 127;
    float beta = logf(1.0f / (float)(l + 1) + 1.0f);
    float v = beta * W[idx];
    if (k == n) v += 1.0f - beta;
    Wt[(size_t)l * HID * HID + n * HID + k] = f2bf(v);
  }
}

static __global__ void k_cvtw2(const float* __restrict__ W2, unsigned short* __restrict__ Wt2) {
  int idx = blockIdx.x * 256 + threadIdx.x;
  if (idx < 48 * HID) {
    int n = idx >> 7, k = idx & 127;
    Wt2[idx] = (n < OUTC) ? f2bf(W2[(size_t)k * OUTC + n]) : 0;
  }
}

// ---------------- lin1: C16[newid] = bf16(relu(A32[perm[newid]] @ W + bias)) ----------------
__global__ __launch_bounds__(256, 3) void k_lin1(
    const float* __restrict__ A32, const unsigned short* __restrict__ Wt16,
    const float* __restrict__ bias, const int* __restrict__ perm,
    unsigned short* __restrict__ C16, int M) {
  __shared__ unsigned short lds[128 * LW];
  const int tid = threadIdx.x;
  const int lane = tid & 63;
  const int wid = tid >> 6;
  const int j = lane & 15, g = lane >> 4;
  const int rowhalf = (wid >> 1) * 64;
  const int colbase = (wid & 1) * 64;
  const int m0 = blockIdx.x * 128;

  f32x4 acc[4][4];
  const f32x4 zero = {0.f, 0.f, 0.f, 0.f};
#pragma unroll
  for (int rt = 0; rt < 4; ++rt)
#pragma unroll
    for (int c = 0; c < 4; ++c) acc[rt][c] = zero;

#pragma unroll 1
  for (int kc = 0; kc < 2; ++kc) {
    bf16x8 bfrag[4][4];
#pragma unroll
    for (int c = 0; c < 4; ++c)
#pragma unroll
      for (int s = 0; s < 4; ++s)
        bfrag[c][s] = *(const bf16x8*)(Wt16 + (size_t)(colbase + 16 * c + j) * INCH +
                                       kc * 128 + 32 * s + 8 * g);
    __syncthreads();
#pragma unroll 2
    for (int i = 0; i < 8; ++i) {
      int idx = i * 256 + tid;
      int row = idx >> 4, ch = idx & 15;
      int grow = m0 + row;
      if (grow >= M) grow = M - 1;
      int orow = perm[grow];
      const float* p = A32 + (size_t)orow * INCH + kc * 128 + ch * 8;
      float4 u0 = *(const float4*)p;
      float4 u1 = *(const float4*)(p + 4);
      bf16x8 v;
      v[0] = (short)f2bf(u0.x); v[1] = (short)f2bf(u0.y);
      v[2] = (short)f2bf(u0.z); v[3] = (short)f2bf(u0.w);
      v[4] = (short)f2bf(u1.x); v[5] = (short)f2bf(u1.y);
      v[6] = (short)f2bf(u1.z); v[7] = (short)f2bf(u1.w);
      *(bf16x8*)&lds[row * LW + ch * 8] = v;
    }
    __syncthreads();
#pragma unroll
    for (int rt = 0; rt < 4; ++rt) {
      bf16x8 af[4];
#pragma unroll
      for (int s = 0; s < 4; ++s)
        af[s] = *(const bf16x8*)&lds[(rowhalf + rt * 16 + j) * LW + 32 * s + 8 * g];
#pragma unroll
      for (int s = 0; s < 4; ++s)
#pragma unroll
        for (int c = 0; c < 4; ++c)
          acc[rt][c] =
              __builtin_amdgcn_mfma_f32_16x16x32_bf16(af[s], bfrag[c][s], acc[rt][c], 0, 0, 0);
    }
  }

#pragma unroll
  for (int rt = 0; rt < 4; ++rt)
#pragma unroll
    for (int i = 0; i < 4; ++i) {
      const int rr = m0 + rowhalf + rt * 16 + 4 * g + i;
      if (rr >= M) continue;
#pragma unroll
      for (int c = 0; c < 4; ++c) {
        const int col = colbase + 16 * c + j;
        float z = fmaxf(acc[rt][c][i] + bias[col], 0.f);
        C16[(size_t)rr * HID + col] = f2bf(z);
      }
    }
}

// ---------------- fused layer: agg (gather) + GEMM, permuted node space ----------------
#define ACC8(V, O, W)                                       \
  acc[(O) + 0] = fmaf((W), bflo((V).x), acc[(O) + 0]);      \
  acc[(O) + 1] = fmaf((W), bfhi((V).x), acc[(O) + 1]);      \
  acc[(O) + 2] = fmaf((W), bflo((V).y), acc[(O) + 2]);      \
  acc[(O) + 3] = fmaf((W), bfhi((V).y), acc[(O) + 3]);      \
  acc[(O) + 4] = fmaf((W), bflo((V).z), acc[(O) + 4]);      \
  acc[(O) + 5] = fmaf((W), bfhi((V).z), acc[(O) + 5]);      \
  acc[(O) + 6] = fmaf((W), bflo((V).w), acc[(O) + 6]);      \
  acc[(O) + 7] = fmaf((W), bfhi((V).w), acc[(O) + 7]);

#define ACCROW(V0, V1, V2, V3, W) \
  ACC8(V0, 0, W) ACC8(V1, 8, W) ACC8(V2, 16, W) ACC8(V3, 24, W)

__global__ __launch_bounds__(256) void k_fused(
    const unsigned short* __restrict__ h16, const unsigned short* __restrict__ x016,
    const float* __restrict__ dinv, const int* __restrict__ offs,
    const int2* __restrict__ edata, const int* __restrict__ perm,
    const unsigned short* __restrict__ Wt16, unsigned short* __restrict__ C16, int M) {
  __shared__ unsigned short lds[64 * LW];
  const int tid = threadIdx.x;
  const int m0 = blockIdx.x * 64;
  const int newid = m0 + (tid >> 2);
  const int cq = (tid & 3) * 32;

  float acc[32];
#pragma unroll
  for (int q = 0; q < 32; ++q) acc[q] = 0.f;

  unsigned short q16[32];
  if (newid < M) {
    const int node = perm[newid];
    int b = offs[node], e = offs[node + 1];
    float dn = dinv[node];
    {  // self loop: own row lives at newid in permuted space
      const unsigned short* p = h16 + (size_t)newid * HID + cq;
      uint4 s0 = *(const uint4*)p, s1 = *(const uint4*)(p + 8);
      uint4 s2 = *(const uint4*)(p + 16), s3 = *(const uint4*)(p + 24);
      float w = dn * dn;
      ACCROW(s0, s1, s2, s3, w)
    }
    int i = b;
    int2 n0, n1;
    if (i + 3 < e) { n0 = edata[i]; n1 = edata[i + 1]; }
    for (; i + 3 < e; i += 2) {
      int2 c0 = n0, c1 = n1;
      n0 = edata[i + 2];
      n1 = edata[i + 3];
      const unsigned short* p0 = h16 + (size_t)c0.x * HID + cq;
      const unsigned short* p1 = h16 + (size_t)c1.x * HID + cq;
      uint4 r0 = *(const uint4*)p0, r1 = *(const uint4*)(p0 + 8);
      uint4 r2 = *(const uint4*)(p0 + 16), r3 = *(const uint4*)(p0 + 24);
      uint4 r4 = *(const uint4*)p1, r5 = *(const uint4*)(p1 + 8);
      uint4 r6 = *(const uint4*)(p1 + 16), r7 = *(const uint4*)(p1 + 24);
      float w0 = __int_as_float(c0.y), w1 = __int_as_float(c1.y);
      ACCROW(r0, r1, r2, r3, w0)
      ACCROW(r4, r5, r6, r7, w1)
    }
    for (; i < e; ++i) {
      int2 e0 = edata[i];
      const unsigned short* p0 = h16 + (size_t)e0.x * HID + cq;
      uint4 r0 = *(const uint4*)p0, r1 = *(const uint4*)(p0 + 8);
      uint4 r2 = *(const uint4*)(p0 + 16), r3 = *(const uint4*)(p0 + 24);
      float w0 = __int_as_float(e0.y);
      ACCROW(r0, r1, r2, r3, w0)
    }
    const unsigned short* px = x016 + (size_t)newid * HID + cq;
    uint4 xa = *(const uint4*)px, xb = *(const uint4*)(px + 8);
    uint4 xc = *(const uint4*)(px + 16), xd = *(const uint4*)(px + 24);
    float xo[32];
#define UNP8(V, O)                                                     \
    xo[(O) + 0] = bflo((V).x); xo[(O) + 1] = bfhi((V).x);              \
    xo[(O) + 2] = bflo((V).y); xo[(O) + 3] = bfhi((V).y);              \
    xo[(O) + 4] = bflo((V).z); xo[(O) + 5] = bfhi((V).z);              \
    xo[(O) + 6] = bflo((V).w); xo[(O) + 7] = bfhi((V).w);
    UNP8(xa, 0) UNP8(xb, 8) UNP8(xc, 16) UNP8(xd, 24)
#undef UNP8
#pragma unroll
    for (int q = 0; q < 32; ++q) q16[q] = f2bf(0.5f * acc[q] + 0.5f * xo[q]);
  } else {
#pragma unroll
    for (int q = 0; q < 32; ++q) q16[q] = 0;
  }
  {
    unsigned short* lrow = &lds[(tid >> 2) * LW + cq];
    *(uint4*)(lrow) = *(const uint4*)&q16[0];
    *(uint4*)(lrow + 8) = *(const uint4*)&q16[8];
    *(uint4*)(lrow + 16) = *(const uint4*)&q16[16];
    *(uint4*)(lrow + 24) = *(const uint4*)&q16[24];
  }
  __syncthreads();

  // phase 2: GEMM 64x128 (skip folded into W'), output stays in permuted space
  const int lane = tid & 63;
  const int wid = tid >> 6;
  const int rq = (wid >> 1) * 32;
  const int colbase = (wid & 1) * 64;
  const int j = lane & 15, g = lane >> 4;

  bf16x8 bfrag[4][4];
#pragma unroll
  for (int c = 0; c < 4; ++c)
#pragma unroll
    for (int s = 0; s < 4; ++s)
      bfrag[c][s] =
          *(const bf16x8*)(Wt16 + (size_t)(colbase + 16 * c + j) * HID + 32 * s + 8 * g);

  const f32x4 zero = {0.f, 0.f, 0.f, 0.f};
#pragma unroll
  for (int rt = 0; rt < 2; ++rt) {
    bf16x8 af[4];
#pragma unroll
    for (int s = 0; s < 4; ++s)
      af[s] = *(const bf16x8*)&lds[(rq + rt * 16 + j) * LW + 32 * s + 8 * g];
    f32x4 a2[4] = {zero, zero, zero, zero};
#pragma unroll
    for (int s = 0; s < 4; ++s)
#pragma unroll
      for (int c = 0; c < 4; ++c)
        a2[c] = __builtin_amdgcn_mfma_f32_16x16x32_bf16(af[s], bfrag[c][s], a2[c], 0, 0, 0);
#pragma unroll
    for (int i = 0; i < 4; ++i) {
      const int rr = m0 + rq + rt * 16 + 4 * g + i;
      if (rr >= M) continue;
#pragma unroll
      for (int c = 0; c < 4; ++c) {
        const int col = colbase + 16 * c + j;
        C16[(size_t)rr * HID + col] = f2bf(fmaxf(a2[c][i], 0.f));
      }
    }
  }
}

// ---------------- fused lin2 + log_softmax via MFMA (permuted in, original out) ----------------
static __global__ __launch_bounds__(256, 3) void k_mlin2(
    const unsigned short* __restrict__ h16, const unsigned short* __restrict__ Wt2,
    const float* __restrict__ b2, const int* __restrict__ perm,
    float* __restrict__ out) {
  __shared__ unsigned short lds[128 * LW];
  const int tid = threadIdx.x;
  const int lane = tid & 63;
  const int wid = tid >> 6;
  const int j = lane & 15, g = lane >> 4;
  const int m0 = blockIdx.x * 128;

  bf16x8 bfrag[3][4];
#pragma unroll
  for (int c = 0; c < 3; ++c)
#pragma unroll
    for (int s = 0; s < 4; ++s)
      bfrag[c][s] = *(const bf16x8*)(Wt2 + (size_t)(16 * c + j) * HID + 32 * s + 8 * g);

  float bb[3];
#pragma unroll
  for (int c = 0; c < 3; ++c) {
    int col = 16 * c + j;
    bb[c] = (col < OUTC) ? b2[col] : -1e30f;
  }

#pragma unroll 2
  for (int i = 0; i < 8; ++i) {
    int idx = i * 256 + tid;
    int row = idx >> 4, ch = idx & 15;
    int grow = m0 + row;
    if (grow >= NN) grow = NN - 1;
    *(bf16x8*)&lds[row * LW + ch * 8] =
        *(const bf16x8*)(h16 + (size_t)grow * HID + ch * 8);
  }
  __syncthreads();

  const f32x4 zero = {0.f, 0.f, 0.f, 0.f};
#pragma unroll
  for (int rt = 0; rt < 2; ++rt) {
    bf16x8 af[4];
#pragma unroll
    for (int s = 0; s < 4; ++s)
      af[s] = *(const bf16x8*)&lds[(wid * 32 + rt * 16 + j) * LW + 32 * s + 8 * g];
    f32x4 acc[3] = {zero, zero, zero};
#pragma unroll
    for (int s = 0; s < 4; ++s)
#pragma unroll
      for (int c = 0; c < 3; ++c)
        acc[c] = __builtin_amdgcn_mfma_f32_16x16x32_bf16(af[s], bfrag[c][s], acc[c], 0, 0, 0);

#pragma unroll
    for (int i = 0; i < 4; ++i) {
      const int rr = m0 + wid * 32 + rt * 16 + 4 * g + i;
      if (rr >= NN) continue;
      float z0 = acc[0][i] + bb[0];
      float z1 = acc[1][i] + bb[1];
      float z2 = acc[2][i] + bb[2];
      float m = fmaxf(fmaxf(z0, z1), z2);
      m = fmaxf(m, __shfl_xor(m, 1));
      m = fmaxf(m, __shfl_xor(m, 2));
      m = fmaxf(m, __shfl_xor(m, 4));
      m = fmaxf(m, __shfl_xor(m, 8));
      float sum = __expf(z0 - m) + __expf(z1 - m) + __expf(z2 - m);
      sum += __shfl_xor(sum, 1);
      sum += __shfl_xor(sum, 2);
      sum += __shfl_xor(sum, 4);
      sum += __shfl_xor(sum, 8);
      float ls = m + logf(sum);
      int orig = perm[rr];
      out[(size_t)orig * OUTC + j] = z0 - ls;
      out[(size_t)orig * OUTC + 16 + j] = z1 - ls;
      if (j < 8) out[(size_t)orig * OUTC + 32 + j] = z2 - ls;
    }
  }
}

// ---------------- host ----------------
extern "C" void kernel_launch(void* const* d_in, const int* in_sizes, int n_in,
                              void* d_out, int out_size, void* d_ws, size_t ws_size,
                              hipStream_t stream) {
  const float* x  = (const float*)d_in[0];
  const int*   ei = (const int*)d_in[1];
  const float* w1 = (const float*)d_in[2];
  const float* b1 = (const float*)d_in[3];
  const float* cw = (const float*)d_in[4];
  const float* w2 = (const float*)d_in[5];
  const float* b2 = (const float*)d_in[6];
  float* out = (float*)d_out;

  char* ws = (char*)d_ws;
  size_t o = 0;
  auto carve = [&](size_t bytes) {
    void* p = ws + o;
    o = (o + bytes + 255) & ~(size_t)255;
    return p;
  };
  float* dinv   = (float*)carve((size_t)NN * 4);
  int*   offs   = (int*)carve((size_t)(NN + 1) * 4);
  int*   cursor = (int*)carve((size_t)NN * 4);
  int*   bcnt   = (int*)carve((size_t)NBUCK * 4);
  int*   boffs  = (int*)carve((size_t)(NBUCK + 1) * 4);
  int*   bcur   = (int*)carve((size_t)NBUCK * 4);
  int*   deg    = (int*)carve((size_t)NN * 4);
  int*   dbin   = (int*)carve(64 * 4);
  int*   dcur   = (int*)carve(64 * 4);
  int*   perm   = (int*)carve((size_t)NN * 4);
  int*   inv    = (int*)carve((size_t)NN * 4);
  int2*  stage  = (int2*)carve((size_t)NE * 8);
  int2*  edata  = (int2*)carve((size_t)NE * 8);
  unsigned short* x016 = (unsigned short*)carve((size_t)NN * HID * 2);
  unsigned short* hbA  = (unsigned short*)carve((size_t)NN * HID * 2);
  unsigned short* hbB  = (unsigned short*)carve((size_t)NN * HID * 2);
  unsigned short* wt1  = (unsigned short*)carve((size_t)INCH * HID * 2);
  unsigned short* wtl  = (unsigned short*)carve((size_t)NLAYERS * HID * HID * 2);
  unsigned short* wt2  = (unsigned short*)carve((size_t)48 * HID * 2);
  (void)ws_size; (void)in_sizes; (void)n_in; (void)out_size;

  const int TB = 256;
  const int gEB = (NE + EPB - 1) / EPB;  // 391

  k_zerob<<<(NBUCK + 255) / 256, TB, 0, stream>>>(bcnt, dbin);
  k_bhist<<<gEB, TB, 0, stream>>>(ei, bcnt);
  k_bscan<<<1, 512, 0, stream>>>(bcnt, boffs, bcur, offs);
  k_sortA<<<gEB, TB, 0, stream>>>(ei, bcur, stage);
  k_degs<<<NBUCK, TB, 0, stream>>>(stage, boffs, offs, dinv, cursor, deg, dbin);
  k_dscan<<<1, 64, 0, stream>>>(dbin, dcur);
  k_perm<<<NBUCK, TB, 0, stream>>>(deg, dcur, perm, inv);
  k_passB2<<<NBUCK, TB, 0, stream>>>(stage, boffs, offs, dinv, inv, cursor, edata);

  k_cvtw<<<(INCH * HID + 255) / 256, 256, 0, stream>>>(w1, wt1, INCH);
  k_cvtw8<<<(NLAYERS * HID * HID + 255) / 256, 256, 0, stream>>>(cw, wtl);
  k_cvtw2<<<(48 * HID + 255) / 256, 256, 0, stream>>>(w2, wt2);

  k_lin1<<<(NN + 127) / 128, 256, 0, stream>>>(x, wt1, b1, perm, x016, NN);

  const int gF = (NN + 63) / 64;  // 1563
  const unsigned short* hin = x016;
  unsigned short* hout = hbA;
  for (int l = 0; l < NLAYERS; ++l) {
    k_fused<<<gF, 256, 0, stream>>>(hin, x016, dinv, offs, edata, perm,
                                    wtl + (size_t)l * HID * HID, hout, NN);
    hin = hout;
    hout = (hout == hbA) ? hbB : hbA;
  }
  k_mlin2<<<(NN + 127) / 128, 256, 0, stream>>>(hin, wt2, b2, perm, out);
}

// Round 14
// 752.569 us; speedup vs baseline: 1.3510x; 1.0155x over previous
//
#include <hip/hip_runtime.h>
#include <math.h>

#define NN 100000
#define NE 1600000
#define HID 128
#define INCH 256
#define OUTC 40
#define NLAYERS 8
#define NBUCK 391   // ceil(NN/256)
#define EPB 4096
#define CAP 6144
#define LW 136      // LDS row stride in ushorts (272 B)

typedef __attribute__((ext_vector_type(8))) short bf16x8;
typedef __attribute__((ext_vector_type(4))) float f32x4;

static __device__ inline unsigned short f2bf(float f) {
  unsigned u = __float_as_uint(f);
  unsigned r = (u + 0x7fff + ((u >> 16) & 1)) >> 16;
  return (unsigned short)r;
}
static __device__ inline float bflo(unsigned u) { return __uint_as_float(u << 16); }
static __device__ inline float bfhi(unsigned u) { return __uint_as_float(u & 0xffff0000u); }

// ---------------- preprocessing (atomic-light counting sort + degree perm) ----------------

static __global__ void k_zerob(int* __restrict__ bcnt, int* __restrict__ dbin) {
  int i = blockIdx.x * 256 + threadIdx.x;
  if (i < NBUCK) bcnt[i] = 0;
  if (i < 64) dbin[i] = 0;
}

static __global__ __launch_bounds__(256) void k_bhist(const int* __restrict__ ei,
                                                      int* __restrict__ bcnt) {
  __shared__ int lh[NBUCK + 1];
  int t = threadIdx.x;
  for (int i = t; i <= NBUCK; i += 256) lh[i] = 0;
  __syncthreads();
  int e0 = blockIdx.x * EPB;
  for (int k = t; k < EPB; k += 256) {
    int e = e0 + k;
    if (e < NE) atomicAdd(&lh[ei[NE + e] >> 8], 1);
  }
  __syncthreads();
  for (int i = t; i < NBUCK; i += 256)
    if (lh[i]) atomicAdd(&bcnt[i], lh[i]);
}

static __global__ void k_bscan(const int* __restrict__ bcnt, int* __restrict__ boffs,
                               int* __restrict__ bcur, int* __restrict__ offs) {
  __shared__ int sd[512];
  int t = threadIdx.x;
  sd[t] = (t < NBUCK) ? bcnt[t] : 0;
  __syncthreads();
  for (int d = 1; d < 512; d <<= 1) {
    int v = (t >= d) ? sd[t - d] : 0;
    __syncthreads();
    sd[t] += v;
    __syncthreads();
  }
  if (t < NBUCK) {
    boffs[t + 1] = sd[t];
    bcur[t] = sd[t] - bcnt[t];
  }
  if (t == 0) { boffs[0] = 0; offs[NN] = NE; }
}

static __global__ __launch_bounds__(256) void k_sortA(const int* __restrict__ ei,
                                                      int* __restrict__ bcur,
                                                      int2* __restrict__ stage) {
  __shared__ int lsrc[EPB], ldst[EPB];
  __shared__ int lh[NBUCK + 1], lbase[NBUCK + 1], lcur[NBUCK + 1];
  int t = threadIdx.x;
  int e0 = blockIdx.x * EPB;
  for (int k = t; k < EPB; k += 256) {
    int e = e0 + k;
    lsrc[k] = (e < NE) ? ei[e] : -1;
    ldst[k] = (e < NE) ? ei[NE + e] : -1;
  }
  for (int i = t; i <= NBUCK; i += 256) lh[i] = 0;
  __syncthreads();
  for (int k = t; k < EPB; k += 256)
    if (ldst[k] >= 0) atomicAdd(&lh[ldst[k] >> 8], 1);
  __syncthreads();
  for (int i = t; i < NBUCK; i += 256) {
    int c = lh[i];
    lbase[i] = c ? atomicAdd(&bcur[i], c) : 0;
    lcur[i] = 0;
  }
  __syncthreads();
  for (int k = t; k < EPB; k += 256) {
    int d = ldst[k];
    if (d >= 0) {
      int bu = d >> 8;
      int r = atomicAdd(&lcur[bu], 1);
      stage[lbase[bu] + r] = make_int2(lsrc[k], d);
    }
  }
}

static __global__ __launch_bounds__(256) void k_degs(
    const int2* __restrict__ stage, const int* __restrict__ boffs,
    int* __restrict__ offs, float* __restrict__ dinv, int* __restrict__ cursor,
    int* __restrict__ deg, int* __restrict__ dbin) {
  __shared__ int lcnt[256];
  __shared__ int sd[256];
  __shared__ int lhd[64];
  int b = blockIdx.x, t = threadIdx.x;
  int sb = boffs[b], se = boffs[b + 1];
  int cntb = se - sb;
  int nb0 = b << 8;
  lcnt[t] = 0;
  if (t < 64) lhd[t] = 0;
  __syncthreads();
  for (int k = t; k < cntb; k += 256) atomicAdd(&lcnt[stage[sb + k].y - nb0], 1);
  __syncthreads();
  int v = lcnt[t];
  sd[t] = v;
  __syncthreads();
  for (int d = 1; d < 256; d <<= 1) {
    int u = (t >= d) ? sd[t - d] : 0;
    __syncthreads();
    sd[t] += u;
    __syncthreads();
  }
  int n = nb0 + t;
  if (n < NN) {
    int o = sb + sd[t] - v;
    offs[n] = o;
    cursor[n] = o;
    dinv[n] = rsqrtf((float)(v + 1));
    deg[n] = v;
    int bin = 63 - (v > 63 ? 63 : v);  // heavy nodes first
    atomicAdd(&lhd[bin], 1);
  }
  __syncthreads();
  if (t < 64 && lhd[t]) atomicAdd(&dbin[t], lhd[t]);
}

static __global__ void k_dscan(const int* __restrict__ dbin, int* __restrict__ dcur) {
  __shared__ int sd[64];
  int t = threadIdx.x;
  sd[t] = dbin[t];
  __syncthreads();
  if (t == 0) {
    int a = 0;
    for (int i = 0; i < 64; ++i) { int v = sd[i]; sd[i] = a; a += v; }
  }
  __syncthreads();
  dcur[t] = sd[t];
}

static __global__ __launch_bounds__(256) void k_perm(const int* __restrict__ deg,
                                                     int* __restrict__ dcur,
                                                     int* __restrict__ perm,
                                                     int* __restrict__ inv) {
  __shared__ int lh[64], lbase[64], lcur[64];
  int t = threadIdx.x;
  int n = blockIdx.x * 256 + t;
  if (t < 64) { lh[t] = 0; lcur[t] = 0; }
  __syncthreads();
  int bin = 0;
  if (n < NN) {
    int d = deg[n];
    bin = 63 - (d > 63 ? 63 : d);
    atomicAdd(&lh[bin], 1);
  }
  __syncthreads();
  if (t < 64) lbase[t] = lh[t] ? atomicAdd(&dcur[t], lh[t]) : 0;
  __syncthreads();
  if (n < NN) {
    int r = atomicAdd(&lcur[bin], 1);
    int pos = lbase[bin] + r;
    perm[pos] = n;
    inv[n] = pos;
  }
}

// edata.x = inv[src] (permuted-space source index)
static __global__ __launch_bounds__(256) void k_passB2(
    const int2* __restrict__ stage, const int* __restrict__ boffs,
    const int* __restrict__ offs, const float* __restrict__ dinv,
    const int* __restrict__ inv, int* __restrict__ cursor, int2* __restrict__ edata) {
  __shared__ int2 lbuf[CAP];
  __shared__ int lcur[256];
  int b = blockIdx.x, t = threadIdx.x;
  int sb = boffs[b], se = boffs[b + 1];
  int cntb = se - sb;
  int nb0 = b << 8;
  if (cntb <= CAP) {
    if (nb0 + t < NN) lcur[t] = offs[nb0 + t] - sb;
    __syncthreads();
    for (int k = t; k < cntb; k += 256) {
      int2 sd_ = stage[sb + k];
      float w = dinv[sd_.x] * dinv[sd_.y];
      int p = atomicAdd(&lcur[sd_.y - nb0], 1);
      lbuf[p] = make_int2(inv[sd_.x], __float_as_int(w));
    }
    __syncthreads();
    for (int k = t; k < cntb; k += 256) edata[sb + k] = lbuf[k];
  } else {
    for (int k = t; k < cntb; k += 256) {
      int2 sd_ = stage[sb + k];
      float w = dinv[sd_.x] * dinv[sd_.y];
      int p = atomicAdd(&cursor[sd_.y], 1);
      edata[p] = make_int2(inv[sd_.x], __float_as_int(w));
    }
  }
}

// ---------------- weight conversion ----------------
static __global__ void k_cvtw(const float* __restrict__ W, unsigned short* __restrict__ Wt,
                              int K) {
  int idx = blockIdx.x * 256 + threadIdx.x;
  if (idx < K * HID) {
    int k = idx >> 7, n = idx & 127;
    Wt[(size_t)n * K + k] = f2bf(W[idx]);
  }
}

// Folded layer weights: W'_l = beta_l * W_l + (1-beta_l) * I, transposed [n][k]
static __global__ void k_cvtw8(const float* __restrict__ W, unsigned short* __restrict__ Wt) {
  int idx = blockIdx.x * 256 + threadIdx.x;
  if (idx < NLAYERS * HID * HID) {
    int l = idx >> 14, rem = idx & 16383;
    int k = rem >> 7, n = rem & 127;
    float beta = logf(1.0f / (float)(l + 1) + 1.0f);
    float v = beta * W[idx];
    if (k == n) v += 1.0f - beta;
    Wt[(size_t)l * HID * HID + n * HID + k] = f2bf(v);
  }
}

static __global__ void k_cvtw2(const float* __restrict__ W2, unsigned short* __restrict__ Wt2) {
  int idx = blockIdx.x * 256 + threadIdx.x;
  if (idx < 48 * HID) {
    int n = idx >> 7, k = idx & 127;
    Wt2[idx] = (n < OUTC) ? f2bf(W2[(size_t)k * OUTC + n]) : 0;
  }
}

// ---------------- lin1: C16[newid] = bf16(relu(A32[perm[newid]] @ W + bias)) ----------------
// 64-row tile, grid = 1563: 4 waves, wave = 32 rows x 64 cols, K chunked 2x128.
// B-fragments loaded AFTER staging to keep peak VGPR low (>=4 blocks/CU).
__global__ __launch_bounds__(256, 4) void k_lin1(
    const float* __restrict__ A32, const unsigned short* __restrict__ Wt16,
    const float* __restrict__ bias, const int* __restrict__ perm,
    unsigned short* __restrict__ C16, int M) {
  __shared__ unsigned short lds[64 * LW];
  __shared__ int lperm[64];
  const int tid = threadIdx.x;
  const int lane = tid & 63;
  const int wid = tid >> 6;
  const int j = lane & 15, g = lane >> 4;
  const int rq = (wid >> 1) * 32;
  const int colbase = (wid & 1) * 64;
  const int m0 = blockIdx.x * 64;

  if (tid < 64) {
    int r = m0 + tid;
    lperm[tid] = perm[r >= M ? M - 1 : r];
  }

  f32x4 acc[2][4];
  const f32x4 zero = {0.f, 0.f, 0.f, 0.f};
#pragma unroll
  for (int rt = 0; rt < 2; ++rt)
#pragma unroll
    for (int c = 0; c < 4; ++c) acc[rt][c] = zero;

#pragma unroll 1
  for (int kc = 0; kc < 2; ++kc) {
    __syncthreads();  // lperm ready (kc=0) / prior LDS reads done (kc=1)
#pragma unroll
    for (int u = 0; u < 4; ++u) {
      int idx = u * 256 + tid;  // 0..1023
      int row = idx >> 4, ch = idx & 15;
      const float* p = A32 + (size_t)lperm[row] * INCH + kc * 128 + ch * 8;
      float4 u0 = *(const float4*)p;
      float4 u1 = *(const float4*)(p + 4);
      bf16x8 v;
      v[0] = (short)f2bf(u0.x); v[1] = (short)f2bf(u0.y);
      v[2] = (short)f2bf(u0.z); v[3] = (short)f2bf(u0.w);
      v[4] = (short)f2bf(u1.x); v[5] = (short)f2bf(u1.y);
      v[6] = (short)f2bf(u1.z); v[7] = (short)f2bf(u1.w);
      *(bf16x8*)&lds[row * LW + ch * 8] = v;
    }
    __syncthreads();
    bf16x8 bfrag[4][4];
#pragma unroll
    for (int c = 0; c < 4; ++c)
#pragma unroll
      for (int s = 0; s < 4; ++s)
        bfrag[c][s] = *(const bf16x8*)(Wt16 + (size_t)(colbase + 16 * c + j) * INCH +
                                       kc * 128 + 32 * s + 8 * g);
#pragma unroll
    for (int rt = 0; rt < 2; ++rt) {
      bf16x8 af[4];
#pragma unroll
      for (int s = 0; s < 4; ++s)
        af[s] = *(const bf16x8*)&lds[(rq + rt * 16 + j) * LW + 32 * s + 8 * g];
#pragma unroll
      for (int s = 0; s < 4; ++s)
#pragma unroll
        for (int c = 0; c < 4; ++c)
          acc[rt][c] =
              __builtin_amdgcn_mfma_f32_16x16x32_bf16(af[s], bfrag[c][s], acc[rt][c], 0, 0, 0);
    }
  }

#pragma unroll
  for (int rt = 0; rt < 2; ++rt)
#pragma unroll
    for (int i = 0; i < 4; ++i) {
      const int rr = m0 + rq + rt * 16 + 4 * g + i;
      if (rr >= M) continue;
#pragma unroll
      for (int c = 0; c < 4; ++c) {
        const int col = colbase + 16 * c + j;
        float z = fmaxf(acc[rt][c][i] + bias[col], 0.f);
        C16[(size_t)rr * HID + col] = f2bf(z);
      }
    }
}

// ---------------- fused layer: agg (gather) + GEMM, permuted node space ----------------
#define ACC8(V, O, W)                                       \
  acc[(O) + 0] = fmaf((W), bflo((V).x), acc[(O) + 0]);      \
  acc[(O) + 1] = fmaf((W), bfhi((V).x), acc[(O) + 1]);      \
  acc[(O) + 2] = fmaf((W), bflo((V).y), acc[(O) + 2]);      \
  acc[(O) + 3] = fmaf((W), bfhi((V).y), acc[(O) + 3]);      \
  acc[(O) + 4] = fmaf((W), bflo((V).z), acc[(O) + 4]);      \
  acc[(O) + 5] = fmaf((W), bfhi((V).z), acc[(O) + 5]);      \
  acc[(O) + 6] = fmaf((W), bflo((V).w), acc[(O) + 6]);      \
  acc[(O) + 7] = fmaf((W), bfhi((V).w), acc[(O) + 7]);

#define ACCROW(V0, V1, V2, V3, W) \
  ACC8(V0, 0, W) ACC8(V1, 8, W) ACC8(V2, 16, W) ACC8(V3, 24, W)

__global__ __launch_bounds__(256) void k_fused(
    const unsigned short* __restrict__ h16, const unsigned short* __restrict__ x016,
    const float* __restrict__ dinv, const int* __restrict__ offs,
    const int2* __restrict__ edata, const int* __restrict__ perm,
    const unsigned short* __restrict__ Wt16, unsigned short* __restrict__ C16, int M) {
  __shared__ unsigned short lds[64 * LW];
  const int tid = threadIdx.x;
  const int m0 = blockIdx.x * 64;
  const int newid = m0 + (tid >> 2);
  const int cq = (tid & 3) * 32;

  float acc[32];
#pragma unroll
  for (int q = 0; q < 32; ++q) acc[q] = 0.f;

  unsigned short q16[32];
  if (newid < M) {
    const int node = perm[newid];
    int b = offs[node], e = offs[node + 1];
    float dn = dinv[node];
    {  // self loop: own row lives at newid in permuted space
      const unsigned short* p = h16 + (size_t)newid * HID + cq;
      uint4 s0 = *(const uint4*)p, s1 = *(const uint4*)(p + 8);
      uint4 s2 = *(const uint4*)(p + 16), s3 = *(const uint4*)(p + 24);
      float w = dn * dn;
      ACCROW(s0, s1, s2, s3, w)
    }
    int i = b;
    int2 n0, n1;
    if (i + 3 < e) { n0 = edata[i]; n1 = edata[i + 1]; }
    for (; i + 3 < e; i += 2) {
      int2 c0 = n0, c1 = n1;
      n0 = edata[i + 2];
      n1 = edata[i + 3];
      const unsigned short* p0 = h16 + (size_t)c0.x * HID + cq;
      const unsigned short* p1 = h16 + (size_t)c1.x * HID + cq;
      uint4 r0 = *(const uint4*)p0, r1 = *(const uint4*)(p0 + 8);
      uint4 r2 = *(const uint4*)(p0 + 16), r3 = *(const uint4*)(p0 + 24);
      uint4 r4 = *(const uint4*)p1, r5 = *(const uint4*)(p1 + 8);
      uint4 r6 = *(const uint4*)(p1 + 16), r7 = *(const uint4*)(p1 + 24);
      float w0 = __int_as_float(c0.y), w1 = __int_as_float(c1.y);
      ACCROW(r0, r1, r2, r3, w0)
      ACCROW(r4, r5, r6, r7, w1)
    }
    for (; i < e; ++i) {
      int2 e0 = edata[i];
      const unsigned short* p0 = h16 + (size_t)e0.x * HID + cq;
      uint4 r0 = *(const uint4*)p0, r1 = *(const uint4*)(p0 + 8);
      uint4 r2 = *(const uint4*)(p0 + 16), r3 = *(const uint4*)(p0 + 24);
      float w0 = __int_as_float(e0.y);
      ACCROW(r0, r1, r2, r3, w0)
    }
    const unsigned short* px = x016 + (size_t)newid * HID + cq;
    uint4 xa = *(const uint4*)px, xb = *(const uint4*)(px + 8);
    uint4 xc = *(const uint4*)(px + 16), xd = *(const uint4*)(px + 24);
    float xo[32];
#define UNP8(V, O)                                                     \
    xo[(O) + 0] = bflo((V).x); xo[(O) + 1] = bfhi((V).x);              \
    xo[(O) + 2] = bflo((V).y); xo[(O) + 3] = bfhi((V).y);              \
    xo[(O) + 4] = bflo((V).z); xo[(O) + 5] = bfhi((V).z);              \
    xo[(O) + 6] = bflo((V).w); xo[(O) + 7] = bfhi((V).w);
    UNP8(xa, 0) UNP8(xb, 8) UNP8(xc, 16) UNP8(xd, 24)
#undef UNP8
#pragma unroll
    for (int q = 0; q < 32; ++q) q16[q] = f2bf(0.5f * acc[q] + 0.5f * xo[q]);
  } else {
#pragma unroll
    for (int q = 0; q < 32; ++q) q16[q] = 0;
  }
  {
    unsigned short* lrow = &lds[(tid >> 2) * LW + cq];
    *(uint4*)(lrow) = *(const uint4*)&q16[0];
    *(uint4*)(lrow + 8) = *(const uint4*)&q16[8];
    *(uint4*)(lrow + 16) = *(const uint4*)&q16[16];
    *(uint4*)(lrow + 24) = *(const uint4*)&q16[24];
  }
  __syncthreads();

  // phase 2: GEMM 64x128 (skip folded into W'), output stays in permuted space
  const int lane = tid & 63;
  const int wid = tid >> 6;
  const int rq = (wid >> 1) * 32;
  const int colbase = (wid & 1) * 64;
  const int j = lane & 15, g = lane >> 4;

  bf16x8 bfrag[4][4];
#pragma unroll
  for (int c = 0; c < 4; ++c)
#pragma unroll
    for (int s = 0; s < 4; ++s)
      bfrag[c][s] =
          *(const bf16x8*)(Wt16 + (size_t)(colbase + 16 * c + j) * HID + 32 * s + 8 * g);

  const f32x4 zero = {0.f, 0.f, 0.f, 0.f};
#pragma unroll
  for (int rt = 0; rt < 2; ++rt) {
    bf16x8 af[4];
#pragma unroll
    for (int s = 0; s < 4; ++s)
      af[s] = *(const bf16x8*)&lds[(rq + rt * 16 + j) * LW + 32 * s + 8 * g];
    f32x4 a2[4] = {zero, zero, zero, zero};
#pragma unroll
    for (int s = 0; s < 4; ++s)
#pragma unroll
      for (int c = 0; c < 4; ++c)
        a2[c] = __builtin_amdgcn_mfma_f32_16x16x32_bf16(af[s], bfrag[c][s], a2[c], 0, 0, 0);
#pragma unroll
    for (int i = 0; i < 4; ++i) {
      const int rr = m0 + rq + rt * 16 + 4 * g + i;
      if (rr >= M) continue;
#pragma unroll
      for (int c = 0; c < 4; ++c) {
        const int col = colbase + 16 * c + j;
        C16[(size_t)rr * HID + col] = f2bf(fmaxf(a2[c][i], 0.f));
      }
    }
  }
}

// ---------------- fused lin2 + log_softmax via MFMA (permuted in, original out) ----------------
static __global__ __launch_bounds__(256, 3) void k_mlin2(
    const unsigned short* __restrict__ h16, const unsigned short* __restrict__ Wt2,
    const float* __restrict__ b2, const int* __restrict__ perm,
    float* __restrict__ out) {
  __shared__ unsigned short lds[128 * LW];
  const int tid = threadIdx.x;
  const int lane = tid & 63;
  const int wid = tid >> 6;
  const int j = lane & 15, g = lane >> 4;
  const int m0 = blockIdx.x * 128;

  bf16x8 bfrag[3][4];
#pragma unroll
  for (int c = 0; c < 3; ++c)
#pragma unroll
    for (int s = 0; s < 4; ++s)
      bfrag[c][s] = *(const bf16x8*)(Wt2 + (size_t)(16 * c + j) * HID + 32 * s + 8 * g);

  float bb[3];
#pragma unroll
  for (int c = 0; c < 3; ++c) {
    int col = 16 * c + j;
    bb[c] = (col < OUTC) ? b2[col] : -1e30f;
  }

#pragma unroll 2
  for (int i = 0; i < 8; ++i) {
    int idx = i * 256 + tid;
    int row = idx >> 4, ch = idx & 15;
    int grow = m0 + row;
    if (grow >= NN) grow = NN - 1;
    *(bf16x8*)&lds[row * LW + ch * 8] =
        *(const bf16x8*)(h16 + (size_t)grow * HID + ch * 8);
  }
  __syncthreads();

  const f32x4 zero = {0.f, 0.f, 0.f, 0.f};
#pragma unroll
  for (int rt = 0; rt < 2; ++rt) {
    bf16x8 af[4];
#pragma unroll
    for (int s = 0; s < 4; ++s)
      af[s] = *(const bf16x8*)&lds[(wid * 32 + rt * 16 + j) * LW + 32 * s + 8 * g];
    f32x4 acc[3] = {zero, zero, zero};
#pragma unroll
    for (int s = 0; s < 4; ++s)
#pragma unroll
      for (int c = 0; c < 3; ++c)
        acc[c] = __builtin_amdgcn_mfma_f32_16x16x32_bf16(af[s], bfrag[c][s], acc[c], 0, 0, 0);

#pragma unroll
    for (int i = 0; i < 4; ++i) {
      const int rr = m0 + wid * 32 + rt * 16 + 4 * g + i;
      if (rr >= NN) continue;
      float z0 = acc[0][i] + bb[0];
      float z1 = acc[1][i] + bb[1];
      float z2 = acc[2][i] + bb[2];
      float m = fmaxf(fmaxf(z0, z1), z2);
      m = fmaxf(m, __shfl_xor(m, 1));
      m = fmaxf(m, __shfl_xor(m, 2));
      m = fmaxf(m, __shfl_xor(m, 4));
      m = fmaxf(m, __shfl_xor(m, 8));
      float sum = __expf(z0 - m) + __expf(z1 - m) + __expf(z2 - m);
      sum += __shfl_xor(sum, 1);
      sum += __shfl_xor(sum, 2);
      sum += __shfl_xor(sum, 4);
      sum += __shfl_xor(sum, 8);
      float ls = m + logf(sum);
      int orig = perm[rr];
      out[(size_t)orig * OUTC + j] = z0 - ls;
      out[(size_t)orig * OUTC + 16 + j] = z1 - ls;
      if (j < 8) out[(size_t)orig * OUTC + 32 + j] = z2 - ls;
    }
  }
}

// ---------------- host ----------------
extern "C" void kernel_launch(void* const* d_in, const int* in_sizes, int n_in,
                              void* d_out, int out_size, void* d_ws, size_t ws_size,
                              hipStream_t stream) {
  const float* x  = (const float*)d_in[0];
  const int*   ei = (const int*)d_in[1];
  const float* w1 = (const float*)d_in[2];
  const float* b1 = (const float*)d_in[3];
  const float* cw = (const float*)d_in[4];
  const float* w2 = (const float*)d_in[5];
  const float* b2 = (const float*)d_in[6];
  float* out = (float*)d_out;

  char* ws = (char*)d_ws;
  size_t o = 0;
  auto carve = [&](size_t bytes) {
    void* p = ws + o;
    o = (o + bytes + 255) & ~(size_t)255;
    return p;
  };
  float* dinv   = (float*)carve((size_t)NN * 4);
  int*   offs   = (int*)carve((size_t)(NN + 1) * 4);
  int*   cursor = (int*)carve((size_t)NN * 4);
  int*   bcnt   = (int*)carve((size_t)NBUCK * 4);
  int*   boffs  = (int*)carve((size_t)(NBUCK + 1) * 4);
  int*   bcur   = (int*)carve((size_t)NBUCK * 4);
  int*   deg    = (int*)carve((size_t)NN * 4);
  int*   dbin   = (int*)carve(64 * 4);
  int*   dcur   = (int*)carve(64 * 4);
  int*   perm   = (int*)carve((size_t)NN * 4);
  int*   inv    = (int*)carve((size_t)NN * 4);
  int2*  stage  = (int2*)carve((size_t)NE * 8);
  int2*  edata  = (int2*)carve((size_t)NE * 8);
  unsigned short* x016 = (unsigned short*)carve((size_t)NN * HID * 2);
  unsigned short* hbA  = (unsigned short*)carve((size_t)NN * HID * 2);
  unsigned short* hbB  = (unsigned short*)carve((size_t)NN * HID * 2);
  unsigned short* wt1  = (unsigned short*)carve((size_t)INCH * HID * 2);
  unsigned short* wtl  = (unsigned short*)carve((size_t)NLAYERS * HID * HID * 2);
  unsigned short* wt2  = (unsigned short*)carve((size_t)48 * HID * 2);
  (void)ws_size; (void)in_sizes; (void)n_in; (void)out_size;

  const int TB = 256;
  const int gEB = (NE + EPB - 1) / EPB;  // 391

  k_zerob<<<(NBUCK + 255) / 256, TB, 0, stream>>>(bcnt, dbin);
  k_bhist<<<gEB, TB, 0, stream>>>(ei, bcnt);
  k_bscan<<<1, 512, 0, stream>>>(bcnt, boffs, bcur, offs);
  k_sortA<<<gEB, TB, 0, stream>>>(ei, bcur, stage);
  k_degs<<<NBUCK, TB, 0, stream>>>(stage, boffs, offs, dinv, cursor, deg, dbin);
  k_dscan<<<1, 64, 0, stream>>>(dbin, dcur);
  k_perm<<<NBUCK, TB, 0, stream>>>(deg, dcur, perm, inv);
  k_passB2<<<NBUCK, TB, 0, stream>>>(stage, boffs, offs, dinv, inv, cursor, edata);

  k_cvtw<<<(INCH * HID + 255) / 256, 256, 0, stream>>>(w1, wt1, INCH);
  k_cvtw8<<<(NLAYERS * HID * HID + 255) / 256, 256, 0, stream>>>(cw, wtl);
  k_cvtw2<<<(48 * HID + 255) / 256, 256, 0, stream>>>(w2, wt2);

  const int gF = (NN + 63) / 64;  // 1563
  k_lin1<<<gF, 256, 0, stream>>>(x, wt1, b1, perm, x016, NN);

  const unsigned short* hin = x016;
  unsigned short* hout = hbA;
  for (int l = 0; l < NLAYERS; ++l) {
    k_fused<<<gF, 256, 0, stream>>>(hin, x016, dinv, offs, edata, perm,
                                    wtl + (size_t)l * HID * HID, hout, NN);
    hin = hout;
    hout = (hout == hbA) ? hbB : hbA;
  }
  k_mlin2<<<(NN + 127) / 128, 256, 0, stream>>>(hin, wt2, b2, perm, out);
}

// Round 15
// 569.489 us; speedup vs baseline: 1.7853x; 1.3215x over previous
//
#include <hip/hip_runtime.h>
#include <math.h>

#define NN 100000
#define NE 1600000
#define HID 128
#define INCH 256
#define OUTC 40
#define NLAYERS 8
#define NBUCK 391   // ceil(NN/256)
#define EPB 4096
#define CAP 6144
#define LW 136      // LDS row stride in ushorts (272 B)

typedef __attribute__((ext_vector_type(8))) short bf16x8;
typedef __attribute__((ext_vector_type(4))) float f32x4;
typedef __attribute__((ext_vector_type(2))) float f32x2;

static __device__ inline unsigned short f2bf(float f) {
  unsigned u = __float_as_uint(f);
  unsigned r = (u + 0x7fff + ((u >> 16) & 1)) >> 16;
  return (unsigned short)r;
}
static __device__ inline float bflo(unsigned u) { return __uint_as_float(u << 16); }
static __device__ inline float bfhi(unsigned u) { return __uint_as_float(u & 0xffff0000u); }
static __device__ inline unsigned char f2fp8(float f) {
  return (unsigned char)(__builtin_amdgcn_cvt_pk_fp8_f32(f, f, 0, false) & 0xff);
}

// ---------------- preprocessing (atomic-light counting sort + degree perm) ----------------

static __global__ void k_zerob(int* __restrict__ bcnt, int* __restrict__ dbin) {
  int i = blockIdx.x * 256 + threadIdx.x;
  if (i < NBUCK) bcnt[i] = 0;
  if (i < 64) dbin[i] = 0;
}

static __global__ __launch_bounds__(256) void k_bhist(const int* __restrict__ ei,
                                                      int* __restrict__ bcnt) {
  __shared__ int lh[NBUCK + 1];
  int t = threadIdx.x;
  for (int i = t; i <= NBUCK; i += 256) lh[i] = 0;
  __syncthreads();
  int e0 = blockIdx.x * EPB;
  for (int k = t; k < EPB; k += 256) {
    int e = e0 + k;
    if (e < NE) atomicAdd(&lh[ei[NE + e] >> 8], 1);
  }
  __syncthreads();
  for (int i = t; i < NBUCK; i += 256)
    if (lh[i]) atomicAdd(&bcnt[i], lh[i]);
}

static __global__ void k_bscan(const int* __restrict__ bcnt, int* __restrict__ boffs,
                               int* __restrict__ bcur, int* __restrict__ offs) {
  __shared__ int sd[512];
  int t = threadIdx.x;
  sd[t] = (t < NBUCK) ? bcnt[t] : 0;
  __syncthreads();
  for (int d = 1; d < 512; d <<= 1) {
    int v = (t >= d) ? sd[t - d] : 0;
    __syncthreads();
    sd[t] += v;
    __syncthreads();
  }
  if (t < NBUCK) {
    boffs[t + 1] = sd[t];
    bcur[t] = sd[t] - bcnt[t];
  }
  if (t == 0) { boffs[0] = 0; offs[NN] = NE; }
}

static __global__ __launch_bounds__(256) void k_sortA(const int* __restrict__ ei,
                                                      int* __restrict__ bcur,
                                                      int2* __restrict__ stage) {
  __shared__ int lsrc[EPB], ldst[EPB];
  __shared__ int lh[NBUCK + 1], lbase[NBUCK + 1], lcur[NBUCK + 1];
  int t = threadIdx.x;
  int e0 = blockIdx.x * EPB;
  for (int k = t; k < EPB; k += 256) {
    int e = e0 + k;
    lsrc[k] = (e < NE) ? ei[e] : -1;
    ldst[k] = (e < NE) ? ei[NE + e] : -1;
  }
  for (int i = t; i <= NBUCK; i += 256) lh[i] = 0;
  __syncthreads();
  for (int k = t; k < EPB; k += 256)
    if (ldst[k] >= 0) atomicAdd(&lh[ldst[k] >> 8], 1);
  __syncthreads();
  for (int i = t; i < NBUCK; i += 256) {
    int c = lh[i];
    lbase[i] = c ? atomicAdd(&bcur[i], c) : 0;
    lcur[i] = 0;
  }
  __syncthreads();
  for (int k = t; k < EPB; k += 256) {
    int d = ldst[k];
    if (d >= 0) {
      int bu = d >> 8;
      int r = atomicAdd(&lcur[bu], 1);
      stage[lbase[bu] + r] = make_int2(lsrc[k], d);
    }
  }
}

static __global__ __launch_bounds__(256) void k_degs(
    const int2* __restrict__ stage, const int* __restrict__ boffs,
    int* __restrict__ offs, float* __restrict__ dinv, int* __restrict__ cursor,
    int* __restrict__ deg, int* __restrict__ dbin) {
  __shared__ int lcnt[256];
  __shared__ int sd[256];
  __shared__ int lhd[64];
  int b = blockIdx.x, t = threadIdx.x;
  int sb = boffs[b], se = boffs[b + 1];
  int cntb = se - sb;
  int nb0 = b << 8;
  lcnt[t] = 0;
  if (t < 64) lhd[t] = 0;
  __syncthreads();
  for (int k = t; k < cntb; k += 256) atomicAdd(&lcnt[stage[sb + k].y - nb0], 1);
  __syncthreads();
  int v = lcnt[t];
  sd[t] = v;
  __syncthreads();
  for (int d = 1; d < 256; d <<= 1) {
    int u = (t >= d) ? sd[t - d] : 0;
    __syncthreads();
    sd[t] += u;
    __syncthreads();
  }
  int n = nb0 + t;
  if (n < NN) {
    int o = sb + sd[t] - v;
    offs[n] = o;
    cursor[n] = o;
    dinv[n] = rsqrtf((float)(v + 1));
    deg[n] = v;
    int bin = 63 - (v > 63 ? 63 : v);  // heavy nodes first
    atomicAdd(&lhd[bin], 1);
  }
  __syncthreads();
  if (t < 64 && lhd[t]) atomicAdd(&dbin[t], lhd[t]);
}

static __global__ void k_dscan(const int* __restrict__ dbin, int* __restrict__ dcur) {
  __shared__ int sd[64];
  int t = threadIdx.x;
  sd[t] = dbin[t];
  __syncthreads();
  if (t == 0) {
    int a = 0;
    for (int i = 0; i < 64; ++i) { int v = sd[i]; sd[i] = a; a += v; }
  }
  __syncthreads();
  dcur[t] = sd[t];
}

static __global__ __launch_bounds__(256) void k_perm(const int* __restrict__ deg,
                                                     int* __restrict__ dcur,
                                                     int* __restrict__ perm,
                                                     int* __restrict__ inv) {
  __shared__ int lh[64], lbase[64], lcur[64];
  int t = threadIdx.x;
  int n = blockIdx.x * 256 + t;
  if (t < 64) { lh[t] = 0; lcur[t] = 0; }
  __syncthreads();
  int bin = 0;
  if (n < NN) {
    int d = deg[n];
    bin = 63 - (d > 63 ? 63 : d);
    atomicAdd(&lh[bin], 1);
  }
  __syncthreads();
  if (t < 64) lbase[t] = lh[t] ? atomicAdd(&dcur[t], lh[t]) : 0;
  __syncthreads();
  if (n < NN) {
    int r = atomicAdd(&lcur[bin], 1);
    int pos = lbase[bin] + r;
    perm[pos] = n;
    inv[n] = pos;
  }
}

// edata.x = inv[src] (permuted-space source index)
static __global__ __launch_bounds__(256) void k_passB2(
    const int2* __restrict__ stage, const int* __restrict__ boffs,
    const int* __restrict__ offs, const float* __restrict__ dinv,
    const int* __restrict__ inv, int* __restrict__ cursor, int2* __restrict__ edata) {
  __shared__ int2 lbuf[CAP];
  __shared__ int lcur[256];
  int b = blockIdx.x, t = threadIdx.x;
  int sb = boffs[b], se = boffs[b + 1];
  int cntb = se - sb;
  int nb0 = b << 8;
  if (cntb <= CAP) {
    if (nb0 + t < NN) lcur[t] = offs[nb0 + t] - sb;
    __syncthreads();
    for (int k = t; k < cntb; k += 256) {
      int2 sd_ = stage[sb + k];
      float w = dinv[sd_.x] * dinv[sd_.y];
      int p = atomicAdd(&lcur[sd_.y - nb0], 1);
      lbuf[p] = make_int2(inv[sd_.x], __float_as_int(w));
    }
    __syncthreads();
    for (int k = t; k < cntb; k += 256) edata[sb + k] = lbuf[k];
  } else {
    for (int k = t; k < cntb; k += 256) {
      int2 sd_ = stage[sb + k];
      float w = dinv[sd_.x] * dinv[sd_.y];
      int p = atomicAdd(&cursor[sd_.y], 1);
      edata[p] = make_int2(inv[sd_.x], __float_as_int(w));
    }
  }
}

// ---------------- weight conversion ----------------
static __global__ void k_cvtw(const float* __restrict__ W, unsigned short* __restrict__ Wt,
                              int K) {
  int idx = blockIdx.x * 256 + threadIdx.x;
  if (idx < K * HID) {
    int k = idx >> 7, n = idx & 127;
    Wt[(size_t)n * K + k] = f2bf(W[idx]);
  }
}

// Folded layer weights: W'_l = beta_l * W_l + (1-beta_l) * I, transposed [n][k]
static __global__ void k_cvtw8(const float* __restrict__ W, unsigned short* __restrict__ Wt) {
  int idx = blockIdx.x * 256 + threadIdx.x;
  if (idx < NLAYERS * HID * HID) {
    int l = idx >> 14, rem = idx & 16383;
    int k = rem >> 7, n = rem & 127;
    float beta = logf(1.0f / (float)(l + 1) + 1.0f);
    float v = beta * W[idx];
    if (k == n) v += 1.0f - beta;
    Wt[(size_t)l * HID * HID + n * HID + k] = f2bf(v);
  }
}

static __global__ void k_cvtw2(const float* __restrict__ W2, unsigned short* __restrict__ Wt2) {
  int idx = blockIdx.x * 256 + threadIdx.x;
  if (idx < 48 * HID) {
    int n = idx >> 7, k = idx & 127;
    Wt2[idx] = (n < OUTC) ? f2bf(W2[(size_t)k * OUTC + n]) : 0;
  }
}

// ---------------- lin1: x016(bf16) + x08(fp8) = relu(A32[perm] @ W + bias) ----------------
__global__ __launch_bounds__(256, 4) void k_lin1(
    const float* __restrict__ A32, const unsigned short* __restrict__ Wt16,
    const float* __restrict__ bias, const int* __restrict__ perm,
    unsigned short* __restrict__ C16, unsigned char* __restrict__ C8, int M) {
  __shared__ unsigned short lds[64 * LW];
  __shared__ int lperm[64];
  const int tid = threadIdx.x;
  const int lane = tid & 63;
  const int wid = tid >> 6;
  const int j = lane & 15, g = lane >> 4;
  const int rq = (wid >> 1) * 32;
  const int colbase = (wid & 1) * 64;
  const int m0 = blockIdx.x * 64;

  if (tid < 64) {
    int r = m0 + tid;
    lperm[tid] = perm[r >= M ? M - 1 : r];
  }

  f32x4 acc[2][4];
  const f32x4 zero = {0.f, 0.f, 0.f, 0.f};
#pragma unroll
  for (int rt = 0; rt < 2; ++rt)
#pragma unroll
    for (int c = 0; c < 4; ++c) acc[rt][c] = zero;

#pragma unroll 1
  for (int kc = 0; kc < 2; ++kc) {
    __syncthreads();
#pragma unroll
    for (int u = 0; u < 4; ++u) {
      int idx = u * 256 + tid;
      int row = idx >> 4, ch = idx & 15;
      const float* p = A32 + (size_t)lperm[row] * INCH + kc * 128 + ch * 8;
      float4 u0 = *(const float4*)p;
      float4 u1 = *(const float4*)(p + 4);
      bf16x8 v;
      v[0] = (short)f2bf(u0.x); v[1] = (short)f2bf(u0.y);
      v[2] = (short)f2bf(u0.z); v[3] = (short)f2bf(u0.w);
      v[4] = (short)f2bf(u1.x); v[5] = (short)f2bf(u1.y);
      v[6] = (short)f2bf(u1.z); v[7] = (short)f2bf(u1.w);
      *(bf16x8*)&lds[row * LW + ch * 8] = v;
    }
    __syncthreads();
    bf16x8 bfrag[4][4];
#pragma unroll
    for (int c = 0; c < 4; ++c)
#pragma unroll
      for (int s = 0; s < 4; ++s)
        bfrag[c][s] = *(const bf16x8*)(Wt16 + (size_t)(colbase + 16 * c + j) * INCH +
                                       kc * 128 + 32 * s + 8 * g);
#pragma unroll
    for (int rt = 0; rt < 2; ++rt) {
      bf16x8 af[4];
#pragma unroll
      for (int s = 0; s < 4; ++s)
        af[s] = *(const bf16x8*)&lds[(rq + rt * 16 + j) * LW + 32 * s + 8 * g];
#pragma unroll
      for (int s = 0; s < 4; ++s)
#pragma unroll
        for (int c = 0; c < 4; ++c)
          acc[rt][c] =
              __builtin_amdgcn_mfma_f32_16x16x32_bf16(af[s], bfrag[c][s], acc[rt][c], 0, 0, 0);
    }
  }

#pragma unroll
  for (int rt = 0; rt < 2; ++rt)
#pragma unroll
    for (int i = 0; i < 4; ++i) {
      const int rr = m0 + rq + rt * 16 + 4 * g + i;
      if (rr >= M) continue;
#pragma unroll
      for (int c = 0; c < 4; ++c) {
        const int col = colbase + 16 * c + j;
        float z = fmaxf(acc[rt][c][i] + bias[col], 0.f);
        C16[(size_t)rr * HID + col] = f2bf(z);
        C8[(size_t)rr * HID + col] = f2fp8(z);
      }
    }
}

// ---------------- fused layer: agg (fp8 gather) + GEMM, permuted node space ----------------
// h8: fp8 e4m3 gather table. hc (bf16) built in LDS. Output: h8out (+C16 on last layer).
#define ACCD(U, O, W)                                                   \
  {                                                                     \
    f32x2 lo_ = __builtin_amdgcn_cvt_pk_f32_fp8((U), false);            \
    f32x2 hi_ = __builtin_amdgcn_cvt_pk_f32_fp8((U), true);             \
    acc[(O) + 0] = fmaf((W), lo_.x, acc[(O) + 0]);                      \
    acc[(O) + 1] = fmaf((W), lo_.y, acc[(O) + 1]);                      \
    acc[(O) + 2] = fmaf((W), hi_.x, acc[(O) + 2]);                      \
    acc[(O) + 3] = fmaf((W), hi_.y, acc[(O) + 3]);                      \
  }

#define ACCROW8(VA, VB, W)                                              \
  ACCD((VA).x, 0, W) ACCD((VA).y, 4, W) ACCD((VA).z, 8, W) ACCD((VA).w, 12, W) \
  ACCD((VB).x, 16, W) ACCD((VB).y, 20, W) ACCD((VB).z, 24, W) ACCD((VB).w, 28, W)

__global__ __launch_bounds__(256) void k_fused(
    const unsigned char* __restrict__ h8, const unsigned short* __restrict__ x016,
    const float* __restrict__ dinv, const int* __restrict__ offs,
    const int2* __restrict__ edata, const int* __restrict__ perm,
    const unsigned short* __restrict__ Wt16, unsigned char* __restrict__ h8out,
    unsigned short* __restrict__ C16, int M) {
  __shared__ unsigned short lds[64 * LW];
  const int tid = threadIdx.x;
  const int m0 = blockIdx.x * 64;
  const int newid = m0 + (tid >> 2);
  const int cq = (tid & 3) * 32;  // channel (and byte) offset within fp8 row

  float acc[32];
#pragma unroll
  for (int q = 0; q < 32; ++q) acc[q] = 0.f;

  unsigned short q16[32];
  if (newid < M) {
    const int node = perm[newid];
    int b = offs[node], e = offs[node + 1];
    float dn = dinv[node];
    {  // self loop
      const unsigned char* p = h8 + (size_t)newid * HID + cq;
      uint4 s0 = *(const uint4*)p, s1 = *(const uint4*)(p + 16);
      float w = dn * dn;
      ACCROW8(s0, s1, w)
    }
    int i = b;
    int2 n0, n1;
    if (i + 3 < e) { n0 = edata[i]; n1 = edata[i + 1]; }
    for (; i + 3 < e; i += 2) {
      int2 c0 = n0, c1 = n1;
      n0 = edata[i + 2];
      n1 = edata[i + 3];
      const unsigned char* p0 = h8 + (size_t)c0.x * HID + cq;
      const unsigned char* p1 = h8 + (size_t)c1.x * HID + cq;
      uint4 r0 = *(const uint4*)p0, r1 = *(const uint4*)(p0 + 16);
      uint4 r2 = *(const uint4*)p1, r3 = *(const uint4*)(p1 + 16);
      float w0 = __int_as_float(c0.y), w1 = __int_as_float(c1.y);
      ACCROW8(r0, r1, w0)
      ACCROW8(r2, r3, w1)
    }
    for (; i < e; ++i) {
      int2 e0 = edata[i];
      const unsigned char* p0 = h8 + (size_t)e0.x * HID + cq;
      uint4 r0 = *(const uint4*)p0, r1 = *(const uint4*)(p0 + 16);
      float w0 = __int_as_float(e0.y);
      ACCROW8(r0, r1, w0)
    }
    // hc = 0.5*acc + 0.5*x0 (bf16 skip) -> bf16
    const unsigned short* px = x016 + (size_t)newid * HID + cq;
    uint4 xa = *(const uint4*)px, xb = *(const uint4*)(px + 8);
    uint4 xc = *(const uint4*)(px + 16), xd = *(const uint4*)(px + 24);
    float xo[32];
#define UNP8(V, O)                                                     \
    xo[(O) + 0] = bflo((V).x); xo[(O) + 1] = bfhi((V).x);              \
    xo[(O) + 2] = bflo((V).y); xo[(O) + 3] = bfhi((V).y);              \
    xo[(O) + 4] = bflo((V).z); xo[(O) + 5] = bfhi((V).z);              \
    xo[(O) + 6] = bflo((V).w); xo[(O) + 7] = bfhi((V).w);
    UNP8(xa, 0) UNP8(xb, 8) UNP8(xc, 16) UNP8(xd, 24)
#undef UNP8
#pragma unroll
    for (int q = 0; q < 32; ++q) q16[q] = f2bf(0.5f * acc[q] + 0.5f * xo[q]);
  } else {
#pragma unroll
    for (int q = 0; q < 32; ++q) q16[q] = 0;
  }
  {
    unsigned short* lrow = &lds[(tid >> 2) * LW + cq];
    *(uint4*)(lrow) = *(const uint4*)&q16[0];
    *(uint4*)(lrow + 8) = *(const uint4*)&q16[8];
    *(uint4*)(lrow + 16) = *(const uint4*)&q16[16];
    *(uint4*)(lrow + 24) = *(const uint4*)&q16[24];
  }
  __syncthreads();

  // phase 2: GEMM 64x128 (skip folded into W')
  const int lane = tid & 63;
  const int wid = tid >> 6;
  const int rq = (wid >> 1) * 32;
  const int colbase = (wid & 1) * 64;
  const int j = lane & 15, g = lane >> 4;

  bf16x8 bfrag[4][4];
#pragma unroll
  for (int c = 0; c < 4; ++c)
#pragma unroll
    for (int s = 0; s < 4; ++s)
      bfrag[c][s] =
          *(const bf16x8*)(Wt16 + (size_t)(colbase + 16 * c + j) * HID + 32 * s + 8 * g);

  const f32x4 zero = {0.f, 0.f, 0.f, 0.f};
#pragma unroll
  for (int rt = 0; rt < 2; ++rt) {
    bf16x8 af[4];
#pragma unroll
    for (int s = 0; s < 4; ++s)
      af[s] = *(const bf16x8*)&lds[(rq + rt * 16 + j) * LW + 32 * s + 8 * g];
    f32x4 a2[4] = {zero, zero, zero, zero};
#pragma unroll
    for (int s = 0; s < 4; ++s)
#pragma unroll
      for (int c = 0; c < 4; ++c)
        a2[c] = __builtin_amdgcn_mfma_f32_16x16x32_bf16(af[s], bfrag[c][s], a2[c], 0, 0, 0);
#pragma unroll
    for (int i = 0; i < 4; ++i) {
      const int rr = m0 + rq + rt * 16 + 4 * g + i;
      if (rr >= M) continue;
#pragma unroll
      for (int c = 0; c < 4; ++c) {
        const int col = colbase + 16 * c + j;
        float z = fmaxf(a2[c][i], 0.f);
        h8out[(size_t)rr * HID + col] = f2fp8(z);
        if (C16) C16[(size_t)rr * HID + col] = f2bf(z);
      }
    }
  }
}

// ---------------- fused lin2 + log_softmax via MFMA (permuted in, original out) ----------------
static __global__ __launch_bounds__(256, 3) void k_mlin2(
    const unsigned short* __restrict__ h16, const unsigned short* __restrict__ Wt2,
    const float* __restrict__ b2, const int* __restrict__ perm,
    float* __restrict__ out) {
  __shared__ unsigned short lds[128 * LW];
  const int tid = threadIdx.x;
  const int lane = tid & 63;
  const int wid = tid >> 6;
  const int j = lane & 15, g = lane >> 4;
  const int m0 = blockIdx.x * 128;

  bf16x8 bfrag[3][4];
#pragma unroll
  for (int c = 0; c < 3; ++c)
#pragma unroll
    for (int s = 0; s < 4; ++s)
      bfrag[c][s] = *(const bf16x8*)(Wt2 + (size_t)(16 * c + j) * HID + 32 * s + 8 * g);

  float bb[3];
#pragma unroll
  for (int c = 0; c < 3; ++c) {
    int col = 16 * c + j;
    bb[c] = (col < OUTC) ? b2[col] : -1e30f;
  }

#pragma unroll 2
  for (int i = 0; i < 8; ++i) {
    int idx = i * 256 + tid;
    int row = idx >> 4, ch = idx & 15;
    int grow = m0 + row;
    if (grow >= NN) grow = NN - 1;
    *(bf16x8*)&lds[row * LW + ch * 8] =
        *(const bf16x8*)(h16 + (size_t)grow * HID + ch * 8);
  }
  __syncthreads();

  const f32x4 zero = {0.f, 0.f, 0.f, 0.f};
#pragma unroll
  for (int rt = 0; rt < 2; ++rt) {
    bf16x8 af[4];
#pragma unroll
    for (int s = 0; s < 4; ++s)
      af[s] = *(const bf16x8*)&lds[(wid * 32 + rt * 16 + j) * LW + 32 * s + 8 * g];
    f32x4 acc[3] = {zero, zero, zero};
#pragma unroll
    for (int s = 0; s < 4; ++s)
#pragma unroll
      for (int c = 0; c < 3; ++c)
        acc[c] = __builtin_amdgcn_mfma_f32_16x16x32_bf16(af[s], bfrag[c][s], acc[c], 0, 0, 0);

#pragma unroll
    for (int i = 0; i < 4; ++i) {
      const int rr = m0 + wid * 32 + rt * 16 + 4 * g + i;
      if (rr >= NN) continue;
      float z0 = acc[0][i] + bb[0];
      float z1 = acc[1][i] + bb[1];
      float z2 = acc[2][i] + bb[2];
      float m = fmaxf(fmaxf(z0, z1), z2);
      m = fmaxf(m, __shfl_xor(m, 1));
      m = fmaxf(m, __shfl_xor(m, 2));
      m = fmaxf(m, __shfl_xor(m, 4));
      m = fmaxf(m, __shfl_xor(m, 8));
      float sum = __expf(z0 - m) + __expf(z1 - m) + __expf(z2 - m);
      sum += __shfl_xor(sum, 1);
      sum += __shfl_xor(sum, 2);
      sum += __shfl_xor(sum, 4);
      sum += __shfl_xor(sum, 8);
      float ls = m + logf(sum);
      int orig = perm[rr];
      out[(size_t)orig * OUTC + j] = z0 - ls;
      out[(size_t)orig * OUTC + 16 + j] = z1 - ls;
      if (j < 8) out[(size_t)orig * OUTC + 32 + j] = z2 - ls;
    }
  }
}

// ---------------- host ----------------
extern "C" void kernel_launch(void* const* d_in, const int* in_sizes, int n_in,
                              void* d_out, int out_size, void* d_ws, size_t ws_size,
                              hipStream_t stream) {
  const float* x  = (const float*)d_in[0];
  const int*   ei = (const int*)d_in[1];
  const float* w1 = (const float*)d_in[2];
  const float* b1 = (const float*)d_in[3];
  const float* cw = (const float*)d_in[4];
  const float* w2 = (const float*)d_in[5];
  const float* b2 = (const float*)d_in[6];
  float* out = (float*)d_out;

  char* ws = (char*)d_ws;
  size_t o = 0;
  auto carve = [&](size_t bytes) {
    void* p = ws + o;
    o = (o + bytes + 255) & ~(size_t)255;
    return p;
  };
  float* dinv   = (float*)carve((size_t)NN * 4);
  int*   offs   = (int*)carve((size_t)(NN + 1) * 4);
  int*   cursor = (int*)carve((size_t)NN * 4);
  int*   bcnt   = (int*)carve((size_t)NBUCK * 4);
  int*   boffs  = (int*)carve((size_t)(NBUCK + 1) * 4);
  int*   bcur   = (int*)carve((size_t)NBUCK * 4);
  int*   deg    = (int*)carve((size_t)NN * 4);
  int*   dbin   = (int*)carve(64 * 4);
  int*   dcur   = (int*)carve(64 * 4);
  int*   perm   = (int*)carve((size_t)NN * 4);
  int*   inv    = (int*)carve((size_t)NN * 4);
  int2*  stage  = (int2*)carve((size_t)NE * 8);
  int2*  edata  = (int2*)carve((size_t)NE * 8);
  unsigned short* x016 = (unsigned short*)carve((size_t)NN * HID * 2);
  unsigned short* hb16 = (unsigned short*)carve((size_t)NN * HID * 2);
  unsigned char*  h8A  = (unsigned char*)carve((size_t)NN * HID);
  unsigned char*  h8B  = (unsigned char*)carve((size_t)NN * HID);
  unsigned short* wt1  = (unsigned short*)carve((size_t)INCH * HID * 2);
  unsigned short* wtl  = (unsigned short*)carve((size_t)NLAYERS * HID * HID * 2);
  unsigned short* wt2  = (unsigned short*)carve((size_t)48 * HID * 2);
  (void)ws_size; (void)in_sizes; (void)n_in; (void)out_size;

  const int TB = 256;
  const int gEB = (NE + EPB - 1) / EPB;  // 391

  k_zerob<<<(NBUCK + 255) / 256, TB, 0, stream>>>(bcnt, dbin);
  k_bhist<<<gEB, TB, 0, stream>>>(ei, bcnt);
  k_bscan<<<1, 512, 0, stream>>>(bcnt, boffs, bcur, offs);
  k_sortA<<<gEB, TB, 0, stream>>>(ei, bcur, stage);
  k_degs<<<NBUCK, TB, 0, stream>>>(stage, boffs, offs, dinv, cursor, deg, dbin);
  k_dscan<<<1, 64, 0, stream>>>(dbin, dcur);
  k_perm<<<NBUCK, TB, 0, stream>>>(deg, dcur, perm, inv);
  k_passB2<<<NBUCK, TB, 0, stream>>>(stage, boffs, offs, dinv, inv, cursor, edata);

  k_cvtw<<<(INCH * HID + 255) / 256, 256, 0, stream>>>(w1, wt1, INCH);
  k_cvtw8<<<(NLAYERS * HID * HID + 255) / 256, 256, 0, stream>>>(cw, wtl);
  k_cvtw2<<<(48 * HID + 255) / 256, 256, 0, stream>>>(w2, wt2);

  const int gF = (NN + 63) / 64;  // 1563
  k_lin1<<<gF, 256, 0, stream>>>(x, wt1, b1, perm, x016, h8A, NN);

  const unsigned char* hin = h8A;
  unsigned char* hout = h8B;
  for (int l = 0; l < NLAYERS; ++l) {
    unsigned short* c16 = (l == NLAYERS - 1) ? hb16 : nullptr;
    k_fused<<<gF, 256, 0, stream>>>(hin, x016, dinv, offs, edata, perm,
                                    wtl + (size_t)l * HID * HID, hout, c16, NN);
    hin = hout;
    hout = (hout == h8A) ? h8B : h8A;
  }
  k_mlin2<<<(NN + 127) / 128, 256, 0, stream>>>(hb16, wt2, b2, perm, out);
}

// Round 16
// 565.584 us; speedup vs baseline: 1.7977x; 1.0069x over previous
//
#include <hip/hip_runtime.h>
#include <math.h>

#define NN 100000
#define NE 1600000
#define HID 128
#define INCH 256
#define OUTC 40
#define NLAYERS 8
#define NBUCK 391   // ceil(NN/256)
#define EPB 4096
#define CAP 6144
#define LW 136      // LDS row stride in ushorts (272 B)

typedef __attribute__((ext_vector_type(8))) short bf16x8;
typedef __attribute__((ext_vector_type(4))) float f32x4;
typedef __attribute__((ext_vector_type(2))) float f32x2;

static __device__ inline unsigned short f2bf(float f) {
  unsigned u = __float_as_uint(f);
  unsigned r = (u + 0x7fff + ((u >> 16) & 1)) >> 16;
  return (unsigned short)r;
}
static __device__ inline float bflo(unsigned u) { return __uint_as_float(u << 16); }
static __device__ inline float bfhi(unsigned u) { return __uint_as_float(u & 0xffff0000u); }
static __device__ inline unsigned char f2fp8(float f) {
  return (unsigned char)(__builtin_amdgcn_cvt_pk_fp8_f32(f, f, 0, false) & 0xff);
}

// ---------------- preprocessing (atomic-light counting sort + degree perm) ----------------

static __global__ void k_zerob(int* __restrict__ bcnt, int* __restrict__ dbin) {
  int i = blockIdx.x * 256 + threadIdx.x;
  if (i < NBUCK) bcnt[i] = 0;
  if (i < 64) dbin[i] = 0;
}

static __global__ __launch_bounds__(256) void k_bhist(const int* __restrict__ ei,
                                                      int* __restrict__ bcnt) {
  __shared__ int lh[NBUCK + 1];
  int t = threadIdx.x;
  for (int i = t; i <= NBUCK; i += 256) lh[i] = 0;
  __syncthreads();
  int e0 = blockIdx.x * EPB;
  for (int k = t; k < EPB; k += 256) {
    int e = e0 + k;
    if (e < NE) atomicAdd(&lh[ei[NE + e] >> 8], 1);
  }
  __syncthreads();
  for (int i = t; i < NBUCK; i += 256)
    if (lh[i]) atomicAdd(&bcnt[i], lh[i]);
}

static __global__ void k_bscan(const int* __restrict__ bcnt, int* __restrict__ boffs,
                               int* __restrict__ bcur, int* __restrict__ offs) {
  __shared__ int sd[512];
  int t = threadIdx.x;
  sd[t] = (t < NBUCK) ? bcnt[t] : 0;
  __syncthreads();
  for (int d = 1; d < 512; d <<= 1) {
    int v = (t >= d) ? sd[t - d] : 0;
    __syncthreads();
    sd[t] += v;
    __syncthreads();
  }
  if (t < NBUCK) {
    boffs[t + 1] = sd[t];
    bcur[t] = sd[t] - bcnt[t];
  }
  if (t == 0) { boffs[0] = 0; offs[NN] = NE; }
}

static __global__ __launch_bounds__(256) void k_sortA(const int* __restrict__ ei,
                                                      int* __restrict__ bcur,
                                                      int2* __restrict__ stage) {
  __shared__ int lsrc[EPB], ldst[EPB];
  __shared__ int lh[NBUCK + 1], lbase[NBUCK + 1], lcur[NBUCK + 1];
  int t = threadIdx.x;
  int e0 = blockIdx.x * EPB;
  for (int k = t; k < EPB; k += 256) {
    int e = e0 + k;
    lsrc[k] = (e < NE) ? ei[e] : -1;
    ldst[k] = (e < NE) ? ei[NE + e] : -1;
  }
  for (int i = t; i <= NBUCK; i += 256) lh[i] = 0;
  __syncthreads();
  for (int k = t; k < EPB; k += 256)
    if (ldst[k] >= 0) atomicAdd(&lh[ldst[k] >> 8], 1);
  __syncthreads();
  for (int i = t; i < NBUCK; i += 256) {
    int c = lh[i];
    lbase[i] = c ? atomicAdd(&bcur[i], c) : 0;
    lcur[i] = 0;
  }
  __syncthreads();
  for (int k = t; k < EPB; k += 256) {
    int d = ldst[k];
    if (d >= 0) {
      int bu = d >> 8;
      int r = atomicAdd(&lcur[bu], 1);
      stage[lbase[bu] + r] = make_int2(lsrc[k], d);
    }
  }
}

static __global__ __launch_bounds__(256) void k_degs(
    const int2* __restrict__ stage, const int* __restrict__ boffs,
    int* __restrict__ offs, float* __restrict__ dinv, int* __restrict__ cursor,
    int* __restrict__ deg, int* __restrict__ dbin) {
  __shared__ int lcnt[256];
  __shared__ int sd[256];
  __shared__ int lhd[64];
  int b = blockIdx.x, t = threadIdx.x;
  int sb = boffs[b], se = boffs[b + 1];
  int cntb = se - sb;
  int nb0 = b << 8;
  lcnt[t] = 0;
  if (t < 64) lhd[t] = 0;
  __syncthreads();
  for (int k = t; k < cntb; k += 256) atomicAdd(&lcnt[stage[sb + k].y - nb0], 1);
  __syncthreads();
  int v = lcnt[t];
  sd[t] = v;
  __syncthreads();
  for (int d = 1; d < 256; d <<= 1) {
    int u = (t >= d) ? sd[t - d] : 0;
    __syncthreads();
    sd[t] += u;
    __syncthreads();
  }
  int n = nb0 + t;
  if (n < NN) {
    int o = sb + sd[t] - v;
    offs[n] = o;
    cursor[n] = o;
    dinv[n] = rsqrtf((float)(v + 1));
    deg[n] = v;
    int bin = 63 - (v > 63 ? 63 : v);  // heavy nodes first
    atomicAdd(&lhd[bin], 1);
  }
  __syncthreads();
  if (t < 64 && lhd[t]) atomicAdd(&dbin[t], lhd[t]);
}

static __global__ void k_dscan(const int* __restrict__ dbin, int* __restrict__ dcur) {
  __shared__ int sd[64];
  int t = threadIdx.x;
  sd[t] = dbin[t];
  __syncthreads();
  if (t == 0) {
    int a = 0;
    for (int i = 0; i < 64; ++i) { int v = sd[i]; sd[i] = a; a += v; }
  }
  __syncthreads();
  dcur[t] = sd[t];
}

static __global__ __launch_bounds__(256) void k_perm(const int* __restrict__ deg,
                                                     int* __restrict__ dcur,
                                                     int* __restrict__ perm,
                                                     int* __restrict__ inv) {
  __shared__ int lh[64], lbase[64], lcur[64];
  int t = threadIdx.x;
  int n = blockIdx.x * 256 + t;
  if (t < 64) { lh[t] = 0; lcur[t] = 0; }
  __syncthreads();
  int bin = 0;
  if (n < NN) {
    int d = deg[n];
    bin = 63 - (d > 63 ? 63 : d);
    atomicAdd(&lh[bin], 1);
  }
  __syncthreads();
  if (t < 64) lbase[t] = lh[t] ? atomicAdd(&dcur[t], lh[t]) : 0;
  __syncthreads();
  if (n < NN) {
    int r = atomicAdd(&lcur[bin], 1);
    int pos = lbase[bin] + r;
    perm[pos] = n;
    inv[n] = pos;
  }
}

// edata.x = inv[src] (permuted-space source index)
static __global__ __launch_bounds__(256) void k_passB2(
    const int2* __restrict__ stage, const int* __restrict__ boffs,
    const int* __restrict__ offs, const float* __restrict__ dinv,
    const int* __restrict__ inv, int* __restrict__ cursor, int2* __restrict__ edata) {
  __shared__ int2 lbuf[CAP];
  __shared__ int lcur[256];
  int b = blockIdx.x, t = threadIdx.x;
  int sb = boffs[b], se = boffs[b + 1];
  int cntb = se - sb;
  int nb0 = b << 8;
  if (cntb <= CAP) {
    if (nb0 + t < NN) lcur[t] = offs[nb0 + t] - sb;
    __syncthreads();
    for (int k = t; k < cntb; k += 256) {
      int2 sd_ = stage[sb + k];
      float w = dinv[sd_.x] * dinv[sd_.y];
      int p = atomicAdd(&lcur[sd_.y - nb0], 1);
      lbuf[p] = make_int2(inv[sd_.x], __float_as_int(w));
    }
    __syncthreads();
    for (int k = t; k < cntb; k += 256) edata[sb + k] = lbuf[k];
  } else {
    for (int k = t; k < cntb; k += 256) {
      int2 sd_ = stage[sb + k];
      float w = dinv[sd_.x] * dinv[sd_.y];
      int p = atomicAdd(&cursor[sd_.y], 1);
      edata[p] = make_int2(inv[sd_.x], __float_as_int(w));
    }
  }
}

// ---------------- weight conversion ----------------
static __global__ void k_cvtw(const float* __restrict__ W, unsigned short* __restrict__ Wt,
                              int K) {
  int idx = blockIdx.x * 256 + threadIdx.x;
  if (idx < K * HID) {
    int k = idx >> 7, n = idx & 127;
    Wt[(size_t)n * K + k] = f2bf(W[idx]);
  }
}

// Folded layer weights: W'_l = beta_l * W_l + (1-beta_l) * I, transposed [n][k]
static __global__ void k_cvtw8(const float* __restrict__ W, unsigned short* __restrict__ Wt) {
  int idx = blockIdx.x * 256 + threadIdx.x;
  if (idx < NLAYERS * HID * HID) {
    int l = idx >> 14, rem = idx & 16383;
    int k = rem >> 7, n = rem & 127;
    float beta = logf(1.0f / (float)(l + 1) + 1.0f);
    float v = beta * W[idx];
    if (k == n) v += 1.0f - beta;
    Wt[(size_t)l * HID * HID + n * HID + k] = f2bf(v);
  }
}

static __global__ void k_cvtw2(const float* __restrict__ W2, unsigned short* __restrict__ Wt2) {
  int idx = blockIdx.x * 256 + threadIdx.x;
  if (idx < 48 * HID) {
    int n = idx >> 7, k = idx & 127;
    Wt2[idx] = (n < OUTC) ? f2bf(W2[(size_t)k * OUTC + n]) : 0;
  }
}

// ---------------- lin1: streaming reads (original order), scattered row writes ----------
// Block = 64 original rows; x read fully coalesced. Output rows land at inv[orig]:
// result tile staged in LDS, then 64B line-aligned scattered row-chunk writes.
__global__ __launch_bounds__(256, 4) void k_lin1(
    const float* __restrict__ A32, const unsigned short* __restrict__ Wt16,
    const float* __restrict__ bias, const int* __restrict__ inv,
    unsigned short* __restrict__ C16, unsigned char* __restrict__ C8, int M) {
  __shared__ unsigned short lds[64 * LW];
  __shared__ int ldst[64];
  const int tid = threadIdx.x;
  const int lane = tid & 63;
  const int wid = tid >> 6;
  const int j = lane & 15, g = lane >> 4;
  const int rq = (wid >> 1) * 32;
  const int colbase = (wid & 1) * 64;
  const int m0 = blockIdx.x * 64;

  if (tid < 64) {
    int r = m0 + tid;
    ldst[tid] = inv[r >= M ? M - 1 : r];
  }

  f32x4 acc[2][4];
  const f32x4 zero = {0.f, 0.f, 0.f, 0.f};
#pragma unroll
  for (int rt = 0; rt < 2; ++rt)
#pragma unroll
    for (int c = 0; c < 4; ++c) acc[rt][c] = zero;

#pragma unroll 1
  for (int kc = 0; kc < 2; ++kc) {
    __syncthreads();
#pragma unroll
    for (int u = 0; u < 4; ++u) {
      int idx = u * 256 + tid;
      int row = idx >> 4, ch = idx & 15;
      int grow = m0 + row;
      if (grow >= M) grow = M - 1;
      const float* p = A32 + (size_t)grow * INCH + kc * 128 + ch * 8;
      float4 u0 = *(const float4*)p;
      float4 u1 = *(const float4*)(p + 4);
      bf16x8 v;
      v[0] = (short)f2bf(u0.x); v[1] = (short)f2bf(u0.y);
      v[2] = (short)f2bf(u0.z); v[3] = (short)f2bf(u0.w);
      v[4] = (short)f2bf(u1.x); v[5] = (short)f2bf(u1.y);
      v[6] = (short)f2bf(u1.z); v[7] = (short)f2bf(u1.w);
      *(bf16x8*)&lds[row * LW + ch * 8] = v;
    }
    __syncthreads();
    bf16x8 bfrag[4][4];
#pragma unroll
    for (int c = 0; c < 4; ++c)
#pragma unroll
      for (int s = 0; s < 4; ++s)
        bfrag[c][s] = *(const bf16x8*)(Wt16 + (size_t)(colbase + 16 * c + j) * INCH +
                                       kc * 128 + 32 * s + 8 * g);
#pragma unroll
    for (int rt = 0; rt < 2; ++rt) {
      bf16x8 af[4];
#pragma unroll
      for (int s = 0; s < 4; ++s)
        af[s] = *(const bf16x8*)&lds[(rq + rt * 16 + j) * LW + 32 * s + 8 * g];
#pragma unroll
      for (int s = 0; s < 4; ++s)
#pragma unroll
        for (int c = 0; c < 4; ++c)
          acc[rt][c] =
              __builtin_amdgcn_mfma_f32_16x16x32_bf16(af[s], bfrag[c][s], acc[rt][c], 0, 0, 0);
    }
  }

  // stage result tile (bf16) into LDS
  __syncthreads();
#pragma unroll
  for (int rt = 0; rt < 2; ++rt)
#pragma unroll
    for (int i = 0; i < 4; ++i) {
      const int row = rq + rt * 16 + 4 * g + i;
#pragma unroll
      for (int c = 0; c < 4; ++c) {
        const int col = colbase + 16 * c + j;
        lds[row * LW + col] = f2bf(fmaxf(acc[rt][c][i] + bias[col], 0.f));
      }
    }
  __syncthreads();

  // scattered row-chunk writes: thread -> (row = tid>>2, 32-short chunk = tid&3)
  {
    const int r = tid >> 2, q = tid & 3;
    if (m0 + r < M) {
      const unsigned short* src = &lds[r * LW + q * 32];
      uint4 v0 = *(const uint4*)(src);
      uint4 v1 = *(const uint4*)(src + 8);
      uint4 v2 = *(const uint4*)(src + 16);
      uint4 v3 = *(const uint4*)(src + 24);
      size_t base = (size_t)ldst[r] * HID + q * 32;
      *(uint4*)(C16 + base) = v0;
      *(uint4*)(C16 + base + 8) = v1;
      *(uint4*)(C16 + base + 16) = v2;
      *(uint4*)(C16 + base + 24) = v3;
      unsigned char q8[32];
#pragma unroll
      for (int s = 0; s < 8; ++s) {
        unsigned u0 = ((const unsigned*)&v0)[0];  // silence unused; replaced below
      }
      const unsigned* uu = (const unsigned*)src;
#pragma unroll
      for (int s = 0; s < 16; ++s) {
        unsigned u = uu[s];
        q8[2 * s] = f2fp8(bflo(u));
        q8[2 * s + 1] = f2fp8(bfhi(u));
      }
      *(uint4*)(C8 + base) = *(const uint4*)&q8[0];
      *(uint4*)(C8 + base + 16) = *(const uint4*)&q8[16];
    }
  }
}

// ---------------- fused layer: agg (fp8 gather) + GEMM, permuted node space ----------------
#define ACCD(U, O, W)                                                   \
  {                                                                     \
    f32x2 lo_ = __builtin_amdgcn_cvt_pk_f32_fp8((U), false);            \
    f32x2 hi_ = __builtin_amdgcn_cvt_pk_f32_fp8((U), true);             \
    acc[(O) + 0] = fmaf((W), lo_.x, acc[(O) + 0]);                      \
    acc[(O) + 1] = fmaf((W), lo_.y, acc[(O) + 1]);                      \
    acc[(O) + 2] = fmaf((W), hi_.x, acc[(O) + 2]);                      \
    acc[(O) + 3] = fmaf((W), hi_.y, acc[(O) + 3]);                      \
  }

#define ACCROW8(VA, VB, W)                                              \
  ACCD((VA).x, 0, W) ACCD((VA).y, 4, W) ACCD((VA).z, 8, W) ACCD((VA).w, 12, W) \
  ACCD((VB).x, 16, W) ACCD((VB).y, 20, W) ACCD((VB).z, 24, W) ACCD((VB).w, 28, W)

__global__ __launch_bounds__(256) void k_fused(
    const unsigned char* __restrict__ h8, const unsigned short* __restrict__ x016,
    const float* __restrict__ dinv, const int* __restrict__ offs,
    const int2* __restrict__ edata, const int* __restrict__ perm,
    const unsigned short* __restrict__ Wt16, unsigned char* __restrict__ h8out,
    unsigned short* __restrict__ C16, int M) {
  __shared__ unsigned short lds[64 * LW];
  const int tid = threadIdx.x;
  const int m0 = blockIdx.x * 64;
  const int newid = m0 + (tid >> 2);
  const int cq = (tid & 3) * 32;

  float acc[32];
#pragma unroll
  for (int q = 0; q < 32; ++q) acc[q] = 0.f;

  unsigned short q16[32];
  if (newid < M) {
    const int node = perm[newid];
    int b = offs[node], e = offs[node + 1];
    float dn = dinv[node];
    {  // self loop
      const unsigned char* p = h8 + (size_t)newid * HID + cq;
      uint4 s0 = *(const uint4*)p, s1 = *(const uint4*)(p + 16);
      float w = dn * dn;
      ACCROW8(s0, s1, w)
    }
    int i = b;
    int2 n0, n1;
    if (i + 3 < e) { n0 = edata[i]; n1 = edata[i + 1]; }
    for (; i + 3 < e; i += 2) {
      int2 c0 = n0, c1 = n1;
      n0 = edata[i + 2];
      n1 = edata[i + 3];
      const unsigned char* p0 = h8 + (size_t)c0.x * HID + cq;
      const unsigned char* p1 = h8 + (size_t)c1.x * HID + cq;
      uint4 r0 = *(const uint4*)p0, r1 = *(const uint4*)(p0 + 16);
      uint4 r2 = *(const uint4*)p1, r3 = *(const uint4*)(p1 + 16);
      float w0 = __int_as_float(c0.y), w1 = __int_as_float(c1.y);
      ACCROW8(r0, r1, w0)
      ACCROW8(r2, r3, w1)
    }
    for (; i < e; ++i) {
      int2 e0 = edata[i];
      const unsigned char* p0 = h8 + (size_t)e0.x * HID + cq;
      uint4 r0 = *(const uint4*)p0, r1 = *(const uint4*)(p0 + 16);
      float w0 = __int_as_float(e0.y);
      ACCROW8(r0, r1, w0)
    }
    const unsigned short* px = x016 + (size_t)newid * HID + cq;
    uint4 xa = *(const uint4*)px, xb = *(const uint4*)(px + 8);
    uint4 xc = *(const uint4*)(px + 16), xd = *(const uint4*)(px + 24);
    float xo[32];
#define UNP8(V, O)                                                     \
    xo[(O) + 0] = bflo((V).x); xo[(O) + 1] = bfhi((V).x);              \
    xo[(O) + 2] = bflo((V).y); xo[(O) + 3] = bfhi((V).y);              \
    xo[(O) + 4] = bflo((V).z); xo[(O) + 5] = bfhi((V).z);              \
    xo[(O) + 6] = bflo((V).w); xo[(O) + 7] = bfhi((V).w);
    UNP8(xa, 0) UNP8(xb, 8) UNP8(xc, 16) UNP8(xd, 24)
#undef UNP8
#pragma unroll
    for (int q = 0; q < 32; ++q) q16[q] = f2bf(0.5f * acc[q] + 0.5f * xo[q]);
  } else {
#pragma unroll
    for (int q = 0; q < 32; ++q) q16[q] = 0;
  }
  {
    unsigned short* lrow = &lds[(tid >> 2) * LW + cq];
    *(uint4*)(lrow) = *(const uint4*)&q16[0];
    *(uint4*)(lrow + 8) = *(const uint4*)&q16[8];
    *(uint4*)(lrow + 16) = *(const uint4*)&q16[16];
    *(uint4*)(lrow + 24) = *(const uint4*)&q16[24];
  }
  __syncthreads();

  // phase 2: GEMM 64x128 (skip folded into W')
  const int lane = tid & 63;
  const int wid = tid >> 6;
  const int rq = (wid >> 1) * 32;
  const int colbase = (wid & 1) * 64;
  const int j = lane & 15, g = lane >> 4;

  bf16x8 bfrag[4][4];
#pragma unroll
  for (int c = 0; c < 4; ++c)
#pragma unroll
    for (int s = 0; s < 4; ++s)
      bfrag[c][s] =
          *(const bf16x8*)(Wt16 + (size_t)(colbase + 16 * c + j) * HID + 32 * s + 8 * g);

  const f32x4 zero = {0.f, 0.f, 0.f, 0.f};
#pragma unroll
  for (int rt = 0; rt < 2; ++rt) {
    bf16x8 af[4];
#pragma unroll
    for (int s = 0; s < 4; ++s)
      af[s] = *(const bf16x8*)&lds[(rq + rt * 16 + j) * LW + 32 * s + 8 * g];
    f32x4 a2[4] = {zero, zero, zero, zero};
#pragma unroll
    for (int s = 0; s < 4; ++s)
#pragma unroll
      for (int c = 0; c < 4; ++c)
        a2[c] = __builtin_amdgcn_mfma_f32_16x16x32_bf16(af[s], bfrag[c][s], a2[c], 0, 0, 0);
#pragma unroll
    for (int i = 0; i < 4; ++i) {
      const int rr = m0 + rq + rt * 16 + 4 * g + i;
      if (rr >= M) continue;
#pragma unroll
      for (int c = 0; c < 4; ++c) {
        const int col = colbase + 16 * c + j;
        float z = fmaxf(a2[c][i], 0.f);
        h8out[(size_t)rr * HID + col] = f2fp8(z);
        if (C16) C16[(size_t)rr * HID + col] = f2bf(z);
      }
    }
  }
}

// ---------------- fused lin2 + log_softmax via MFMA (permuted in, original out) ----------------
static __global__ __launch_bounds__(256, 3) void k_mlin2(
    const unsigned short* __restrict__ h16, const unsigned short* __restrict__ Wt2,
    const float* __restrict__ b2, const int* __restrict__ perm,
    float* __restrict__ out) {
  __shared__ unsigned short lds[128 * LW];
  const int tid = threadIdx.x;
  const int lane = tid & 63;
  const int wid = tid >> 6;
  const int j = lane & 15, g = lane >> 4;
  const int m0 = blockIdx.x * 128;

  bf16x8 bfrag[3][4];
#pragma unroll
  for (int c = 0; c < 3; ++c)
#pragma unroll
    for (int s = 0; s < 4; ++s)
      bfrag[c][s] = *(const bf16x8*)(Wt2 + (size_t)(16 * c + j) * HID + 32 * s + 8 * g);

  float bb[3];
#pragma unroll
  for (int c = 0; c < 3; ++c) {
    int col = 16 * c + j;
    bb[c] = (col < OUTC) ? b2[col] : -1e30f;
  }

#pragma unroll 2
  for (int i = 0; i < 8; ++i) {
    int idx = i * 256 + tid;
    int row = idx >> 4, ch = idx & 15;
    int grow = m0 + row;
    if (grow >= NN) grow = NN - 1;
    *(bf16x8*)&lds[row * LW + ch * 8] =
        *(const bf16x8*)(h16 + (size_t)grow * HID + ch * 8);
  }
  __syncthreads();

  const f32x4 zero = {0.f, 0.f, 0.f, 0.f};
#pragma unroll
  for (int rt = 0; rt < 2; ++rt) {
    bf16x8 af[4];
#pragma unroll
    for (int s = 0; s < 4; ++s)
      af[s] = *(const bf16x8*)&lds[(wid * 32 + rt * 16 + j) * LW + 32 * s + 8 * g];
    f32x4 acc[3] = {zero, zero, zero};
#pragma unroll
    for (int s = 0; s < 4; ++s)
#pragma unroll
      for (int c = 0; c < 3; ++c)
        acc[c] = __builtin_amdgcn_mfma_f32_16x16x32_bf16(af[s], bfrag[c][s], acc[c], 0, 0, 0);

#pragma unroll
    for (int i = 0; i < 4; ++i) {
      const int rr = m0 + wid * 32 + rt * 16 + 4 * g + i;
      if (rr >= NN) continue;
      float z0 = acc[0][i] + bb[0];
      float z1 = acc[1][i] + bb[1];
      float z2 = acc[2][i] + bb[2];
      float m = fmaxf(fmaxf(z0, z1), z2);
      m = fmaxf(m, __shfl_xor(m, 1));
      m = fmaxf(m, __shfl_xor(m, 2));
      m = fmaxf(m, __shfl_xor(m, 4));
      m = fmaxf(m, __shfl_xor(m, 8));
      float sum = __expf(z0 - m) + __expf(z1 - m) + __expf(z2 - m);
      sum += __shfl_xor(sum, 1);
      sum += __shfl_xor(sum, 2);
      sum += __shfl_xor(sum, 4);
      sum += __shfl_xor(sum, 8);
      float ls = m + logf(sum);
      int orig = perm[rr];
      out[(size_t)orig * OUTC + j] = z0 - ls;
      out[(size_t)orig * OUTC + 16 + j] = z1 - ls;
      if (j < 8) out[(size_t)orig * OUTC + 32 + j] = z2 - ls;
    }
  }
}

// ---------------- host ----------------
extern "C" void kernel_launch(void* const* d_in, const int* in_sizes, int n_in,
                              void* d_out, int out_size, void* d_ws, size_t ws_size,
                              hipStream_t stream) {
  const float* x  = (const float*)d_in[0];
  const int*   ei = (const int*)d_in[1];
  const float* w1 = (const float*)d_in[2];
  const float* b1 = (const float*)d_in[3];
  const float* cw = (const float*)d_in[4];
  const float* w2 = (const float*)d_in[5];
  const float* b2 = (const float*)d_in[6];
  float* out = (float*)d_out;

  char* ws = (char*)d_ws;
  size_t o = 0;
  auto carve = [&](size_t bytes) {
    void* p = ws + o;
    o = (o + bytes + 255) & ~(size_t)255;
    return p;
  };
  float* dinv   = (float*)carve((size_t)NN * 4);
  int*   offs   = (int*)carve((size_t)(NN + 1) * 4);
  int*   cursor = (int*)carve((size_t)NN * 4);
  int*   bcnt   = (int*)carve((size_t)NBUCK * 4);
  int*   boffs  = (int*)carve((size_t)(NBUCK + 1) * 4);
  int*   bcur   = (int*)carve((size_t)NBUCK * 4);
  int*   deg    = (int*)carve((size_t)NN * 4);
  int*   dbin   = (int*)carve(64 * 4);
  int*   dcur   = (int*)carve(64 * 4);
  int*   perm   = (int*)carve((size_t)NN * 4);
  int*   inv    = (int*)carve((size_t)NN * 4);
  int2*  stage  = (int2*)carve((size_t)NE * 8);
  int2*  edata  = (int2*)carve((size_t)NE * 8);
  unsigned short* x016 = (unsigned short*)carve((size_t)NN * HID * 2);
  unsigned short* hb16 = (unsigned short*)carve((size_t)NN * HID * 2);
  unsigned char*  h8A  = (unsigned char*)carve((size_t)NN * HID);
  unsigned char*  h8B  = (unsigned char*)carve((size_t)NN * HID);
  unsigned short* wt1  = (unsigned short*)carve((size_t)INCH * HID * 2);
  unsigned short* wtl  = (unsigned short*)carve((size_t)NLAYERS * HID * HID * 2);
  unsigned short* wt2  = (unsigned short*)carve((size_t)48 * HID * 2);
  (void)ws_size; (void)in_sizes; (void)n_in; (void)out_size;

  const int TB = 256;
  const int gEB = (NE + EPB - 1) / EPB;  // 391

  k_zerob<<<(NBUCK + 255) / 256, TB, 0, stream>>>(bcnt, dbin);
  k_bhist<<<gEB, TB, 0, stream>>>(ei, bcnt);
  k_bscan<<<1, 512, 0, stream>>>(bcnt, boffs, bcur, offs);
  k_sortA<<<gEB, TB, 0, stream>>>(ei, bcur, stage);
  k_degs<<<NBUCK, TB, 0, stream>>>(stage, boffs, offs, dinv, cursor, deg, dbin);
  k_dscan<<<1, 64, 0, stream>>>(dbin, dcur);
  k_perm<<<NBUCK, TB, 0, stream>>>(deg, dcur, perm, inv);
  k_passB2<<<NBUCK, TB, 0, stream>>>(stage, boffs, offs, dinv, inv, cursor, edata);

  k_cvtw<<<(INCH * HID + 255) / 256, 256, 0, stream>>>(w1, wt1, INCH);
  k_cvtw8<<<(NLAYERS * HID * HID + 255) / 256, 256, 0, stream>>>(cw, wtl);
  k_cvtw2<<<(48 * HID + 255) / 256, 256, 0, stream>>>(w2, wt2);

  const int gF = (NN + 63) / 64;  // 1563
  k_lin1<<<gF, 256, 0, stream>>>(x, wt1, b1, inv, x016, h8A, NN);

  const unsigned char* hin = h8A;
  unsigned char* hout = h8B;
  for (int l = 0; l < NLAYERS; ++l) {
    unsigned short* c16 = (l == NLAYERS - 1) ? hb16 : nullptr;
    k_fused<<<gF, 256, 0, stream>>>(hin, x016, dinv, offs, edata, perm,
                                    wtl + (size_t)l * HID * HID, hout, c16, NN);
    hin = hout;
    hout = (hout == h8A) ? h8B : h8A;
  }
  k_mlin2<<<(NN + 127) / 128, 256, 0, stream>>>(hb16, wt2, b2, perm, out);
}